// Round 6
// baseline (1014.281 us; speedup 1.0000x reference)
//
#include <hip/hip_runtime.h>

#define NN    50000      // nodes
#define NE    800000     // edges (without self loops)
#define NET   850000     // NE + NN (with self loops)
#define NBUCK 196        // dst-buckets of 256 nodes
#define MAXB  8192       // padded slots per bucket
#define GRID  768        // 3 blocks/CU x 256 CUs — co-resident by construction
#define GTILE 782        // (NN+63)/64 gemm row-tiles
#define NGRP  12500      // NN/4 agg node-groups (4 nodes = 4 waves per group)

typedef __fp16 half2_t __attribute__((ext_vector_type(2)));
typedef _Float16 half8 __attribute__((ext_vector_type(8)));
typedef float floatx4 __attribute__((ext_vector_type(4)));

__device__ __forceinline__ float lrelu(float v) { return fmaxf(v, 0.2f * v); }
__device__ __forceinline__ unsigned pk16(float a, float b) {
    half2_t h = __builtin_amdgcn_cvt_pkrtz(a, b);
    return __builtin_bit_cast(unsigned, h);
}
__device__ __forceinline__ float2 unpk16(unsigned u) {
    half2_t h = __builtin_bit_cast(half2_t, u);
    return make_float2((float)h.x, (float)h.y);
}

// Device-scope grid barrier. bar[0]=arrival count, bar[16]=generation
// (separate 64B lines). Requires all blocks co-resident (GRID = 3/CU).
// __syncthreads drains each thread's stores to L2; t0's __threadfence
// emits wbl2/inv so cross-XCD readers see them (Guideline 16).
// Bounded spin: on pathological non-residency we break (wrong answer,
// verification fails visibly) instead of hanging the harness.
__device__ __forceinline__ void gridbar(int* bar, int nb) {
    __syncthreads();
    if (threadIdx.x == 0) {
        __threadfence();
        const int gen = __hip_atomic_load(bar + 16, __ATOMIC_RELAXED, __HIP_MEMORY_SCOPE_AGENT);
        const int arr = __hip_atomic_fetch_add(bar, 1, __ATOMIC_ACQ_REL, __HIP_MEMORY_SCOPE_AGENT);
        if (arr == nb - 1) {
            __hip_atomic_store(bar, 0, __ATOMIC_RELAXED, __HIP_MEMORY_SCOPE_AGENT);
            __hip_atomic_fetch_add(bar + 16, 1, __ATOMIC_RELEASE, __HIP_MEMORY_SCOPE_AGENT);
        } else {
            int spins = 0;
            while (__hip_atomic_load(bar + 16, __ATOMIC_ACQUIRE, __HIP_MEMORY_SCOPE_AGENT) == gen) {
                __builtin_amdgcn_s_sleep(2);
                if (++spins > (1 << 18)) break;   // failsafe
            }
        }
        __threadfence();
    }
    __syncthreads();
}

// ---------------------------------------------------------------------------
// Fused GAT pipeline: P0 prep -> P1 bin -> P2 bsort||gemm1 -> P3 agg1
// -> P4 gemm2 -> P5 agg2. One launch instead of seven.
// ---------------------------------------------------------------------------
__global__ __launch_bounds__(256, 3) void fused_gat_kernel(
    const float* __restrict__ x, const int* __restrict__ ei,
    const float* __restrict__ W1, const float* __restrict__ W2,
    const float* __restrict__ at_s1, const float* __restrict__ at_d1,
    const float* __restrict__ b1,
    const float* __restrict__ at_s2, const float* __restrict__ at_d2,
    const float* __restrict__ b2,
    _Float16* __restrict__ w1t, _Float16* __restrict__ w2t,
    int* __restrict__ bcnt, unsigned* __restrict__ pairs,
    int* __restrict__ row_beg, int* __restrict__ row_end, int* __restrict__ col,
    float* __restrict__ as1, float* __restrict__ ad1,
    float* __restrict__ as2, float* __restrict__ ad2,
    _Float16* __restrict__ h1h, _Float16* __restrict__ act1h,
    _Float16* __restrict__ h2h, float* __restrict__ out,
    int* __restrict__ bar)
{
    __shared__ __align__(16) char smem[35840];   // max over phases (bsort 35KB)
    const int t    = threadIdx.x;
    const int bid  = blockIdx.x;
    const int nb   = gridDim.x;
    const int lane = t & 63;
    const int wv   = t >> 6;

    // ================= P0: zero bcnt + folded weight prep =================
    for (int i = bid * 256 + t; i < 4096; i += nb * 256) bcnt[i] = 0;
    for (int idx = bid * 256 + t; idx < 24576; idx += nb * 256) {
        if (idx < 16384) {
            w1t[(idx & 127) * 128 + (idx >> 7)] = (_Float16)W1[idx];
        } else {
            const int j = idx - 16384;
            w2t[(j & 63) * 128 + (j >> 6)] = (_Float16)W2[j];
        }
    }
    gridbar(bar, nb);

    // ================= P1: bin (grid-stride histogram + scatter) ==========
    {
        int* hist = (int*)smem;
        int* base = hist + NBUCK;
        int* cur  = base + NBUCK;
        if (t < NBUCK) { hist[t] = 0; cur[t] = 0; }
        __syncthreads();
        for (int e = bid * 256 + t; e < NET; e += nb * 256) {
            const int d = (e < NE) ? ei[NE + e] : (e - NE);
            atomicAdd(&hist[d >> 8], 1);
        }
        __syncthreads();
        if (t < NBUCK && hist[t]) base[t] = atomicAdd(&bcnt[t * 16], hist[t]);
        __syncthreads();
        for (int e = bid * 256 + t; e < NET; e += nb * 256) {
            int s, d;
            if (e < NE) { s = ei[e]; d = ei[NE + e]; } else { s = d = e - NE; }
            const int bk = d >> 8;
            const int r = atomicAdd(&cur[bk], 1);
            pairs[(size_t)bk * MAXB + base[bk] + r] =
                (unsigned)s | ((unsigned)(d & 255) << 16);
        }
    }
    gridbar(bar, nb);

    // ================= P2: bsort (vt<NBUCK) || gemm1 (else) ===============
    for (int vt = bid; vt < NBUCK + GTILE; vt += nb) {
        if (vt < NBUCK) {
            // ---- bsort bucket vt with 256 threads ----
            const int b = vt;
            int* hist = (int*)smem;
            int* cur  = hist + 256;
            int* sh   = cur + 256;
            int* outl = sh + 256;                 // MAXB ints = 32KB
            const int m = bcnt[b * 16];
            const int gbase = b * MAXB;
            hist[t] = 0;
            __syncthreads();
            for (int i = t; i < m; i += 256)
                atomicAdd(&hist[pairs[gbase + i] >> 16], 1);
            __syncthreads();
            sh[t] = hist[t];
            __syncthreads();
#pragma unroll
            for (int off = 1; off < 256; off <<= 1) {
                const int u = (t >= off) ? sh[t - off] : 0;
                __syncthreads();
                sh[t] += u;
                __syncthreads();
            }
            {
                const int ex = sh[t] - hist[t];
                cur[t] = ex;
                const int node = (b << 8) + t;
                if (node < NN) {
                    row_beg[node] = gbase + ex;
                    row_end[node] = gbase + ex + hist[t];
                }
            }
            __syncthreads();
            for (int i = t; i < m; i += 256) {
                const unsigned p = pairs[gbase + i];
                const int r = atomicAdd(&cur[p >> 16], 1);
                outl[r] = (int)(p & 0xFFFFu);
            }
            __syncthreads();
            for (int i = t; i < m; i += 256) col[gbase + i] = outl[i];
        } else {
            // ---- gemm1 tile (R13 internals, LDS lw->hs aliased) ----
            const int tile = vt - NBUCK;
            _Float16* lw = (_Float16*)smem;       // 32KB swizzled W1^T
            const int m  = lane & 15;
            const int q  = lane >> 4;
            const int gr0 = tile * 64;
            const int rme = gr0 + wv * 16 + m;
            const int rc  = rme < NN ? rme : NN - 1;
            const float* ap = x + (size_t)rc * 128 + q * 8;

            float4 f0[4], f1[4];
#pragma unroll
            for (int ks = 0; ks < 4; ks++) {
                f0[ks] = *(const float4*)(ap + ks * 32);
                f1[ks] = *(const float4*)(ap + ks * 32 + 4);
            }
            {
                const int kb = t & 15;
                const int n0 = t >> 4;
#pragma unroll
                for (int it = 0; it < 8; it++) {
                    const int n = n0 + it * 16;
                    const uint4 v = *(const uint4*)(w1t + n * 128 + kb * 8);
                    *(uint4*)((char*)lw + n * 256 + ((kb * 16) ^ ((n & 7) << 4))) = v;
                }
            }
            __syncthreads();

            floatx4 acc[8];
#pragma unroll
            for (int nt = 0; nt < 8; nt++) acc[nt] = (floatx4){0.f, 0.f, 0.f, 0.f};
            const int swz = (m & 7) << 4;
#pragma unroll
            for (int ks = 0; ks < 4; ks++) {
                const uint4 au = make_uint4(pk16(f0[ks].x, f0[ks].y), pk16(f0[ks].z, f0[ks].w),
                                            pk16(f1[ks].x, f1[ks].y), pk16(f1[ks].z, f1[ks].w));
                const half8 a = __builtin_bit_cast(half8, au);
#pragma unroll
                for (int nt = 0; nt < 8; nt++) {
                    const int n = nt * 16 + m;
                    const half8 b = *(const half8*)((const char*)lw + n * 256 +
                                                    ((ks * 64 + q * 16) ^ swz));
                    acc[nt] = __builtin_amdgcn_mfma_f32_16x16x32_f16(a, b, acc[nt], 0, 0, 0);
                }
            }
            __syncthreads();                      // lw reads done; alias as hs
            _Float16* hs = (_Float16*)smem;       // 16KB
            const int lrow0 = wv * 16 + q * 4;
#pragma unroll
            for (int nt = 0; nt < 8; nt++)
#pragma unroll
                for (int r = 0; r < 4; r++)
                    hs[(lrow0 + r) * 128 + nt * 16 + m] = (_Float16)acc[nt][r];
            __syncthreads();

#pragma unroll
            for (int i = t; i < 1024; i += 256) {
                const int row = i >> 4;
                if (gr0 + row < NN)
                    ((half8*)h1h)[(size_t)(gr0 + row) * 16 + (i & 15)] = ((const half8*)hs)[i];
            }
            const int arow = t >> 2, hd = t & 3;
            const int grow = gr0 + arow;
            float ps = 0.f, pd = 0.f;
            const half8*  hp8 = (const half8*)(hs + arow * 128 + hd * 32);
            const float4* s4  = (const float4*)(at_s1 + hd * 32);
            const float4* d4  = (const float4*)(at_d1 + hd * 32);
#pragma unroll
            for (int cc = 0; cc < 4; cc++) {
                const half8 hv = hp8[cc];
                const float4 a = s4[cc * 2], b = s4[cc * 2 + 1];
                const float4 c = d4[cc * 2], e = d4[cc * 2 + 1];
                ps += (float)hv[0]*a.x + (float)hv[1]*a.y + (float)hv[2]*a.z + (float)hv[3]*a.w
                    + (float)hv[4]*b.x + (float)hv[5]*b.y + (float)hv[6]*b.z + (float)hv[7]*b.w;
                pd += (float)hv[0]*c.x + (float)hv[1]*c.y + (float)hv[2]*c.z + (float)hv[3]*c.w
                    + (float)hv[4]*e.x + (float)hv[5]*e.y + (float)hv[6]*e.z + (float)hv[7]*e.w;
            }
            if (grow < NN) {
                as1[grow * 4 + hd] = ps;
                ad1[grow * 4 + hd] = pd;
            }
        }
        __syncthreads();   // LDS reuse across vt tasks
    }
    gridbar(bar, nb);

    // ================= P3: agg1 (grid-stride node groups) =================
    {
        float* wbuf = (float*)smem;               // 4 waves x 256 floats
        const int head = lane >> 4;
        float* wb = wbuf + wv * 256;
        for (int vb = bid; vb < NGRP; vb += nb) {
            const int d = __builtin_amdgcn_readfirstlane(vb * 4 + wv);
            const int beg = row_beg[d], end = row_end[d];
            const float4 ad4 = ((const float4*)ad1)[d];
            float acc0 = 0.f, acc1 = 0.f, den = 0.f;

            for (int jb = beg; jb < end; jb += 64) {
                const int cnt = min(64, end - jb);
                {
                    const int sl = col[jb + min(lane, cnt - 1)];
                    const float4 a = ((const float4*)as1)[sl];
                    float4 w4;
                    w4.x = __expf(lrelu(a.x + ad4.x));
                    w4.y = __expf(lrelu(a.y + ad4.y));
                    w4.z = __expf(lrelu(a.z + ad4.z));
                    w4.w = __expf(lrelu(a.w + ad4.w));
                    ((float4*)wb)[lane] = w4;
                }
                __asm__ volatile("s_waitcnt lgkmcnt(0)" ::: "memory");

                const unsigned* hh = (const unsigned*)h1h;
                int k = 0;
                for (; k + 16 <= cnt; k += 16) {
                    float    w[16];
                    unsigned g[16];
#pragma unroll
                    for (int u = 0; u < 16; u++) {
                        const int s = col[jb + k + u];
                        w[u] = wb[(k + u) * 4 + head];
                        g[u] = hh[s * 64 + lane];
                    }
#pragma unroll
                    for (int u = 0; u < 16; u++) {
                        const float2 g2 = unpk16(g[u]);
                        den  += w[u];
                        acc0 += w[u] * g2.x;
                        acc1 += w[u] * g2.y;
                    }
                }
                for (; k + 4 <= cnt; k += 4) {
                    float    w[4];
                    unsigned g[4];
#pragma unroll
                    for (int u = 0; u < 4; u++) {
                        const int s = col[jb + k + u];
                        w[u] = wb[(k + u) * 4 + head];
                        g[u] = hh[s * 64 + lane];
                    }
#pragma unroll
                    for (int u = 0; u < 4; u++) {
                        const float2 g2 = unpk16(g[u]);
                        den  += w[u];
                        acc0 += w[u] * g2.x;
                        acc1 += w[u] * g2.y;
                    }
                }
                for (; k < cnt; k++) {
                    const float w = wb[k * 4 + head];
                    const float2 g2 = unpk16(hh[col[jb + k] * 64 + lane]);
                    den  += w;
                    acc0 += w * g2.x;
                    acc1 += w * g2.y;
                }
                __asm__ volatile("" ::: "memory");
            }
            const float2 bb  = ((const float2*)b1)[lane];
            const float  inv = 1.f / (den + 1e-16f);
            float v0 = acc0 * inv + bb.x;
            float v1 = acc1 * inv + bb.y;
            v0 = v0 > 0.f ? v0 : (__expf(v0) - 1.f);
            v1 = v1 > 0.f ? v1 : (__expf(v1) - 1.f);
            ((unsigned*)act1h)[d * 64 + lane] = pk16(v0, v1);
        }
    }
    gridbar(bar, nb);

    // ================= P4: gemm2 (grid-stride tiles) ======================
    for (int tile = bid; tile < GTILE; tile += nb) {
        _Float16* lw = (_Float16*)smem;           // 16KB swizzled W2^T
        const int m  = lane & 15;
        const int q  = lane >> 4;
        const int gr0 = tile * 64;
        const int rme = gr0 + wv * 16 + m;
        const int rc  = rme < NN ? rme : NN - 1;
        const _Float16* ap = act1h + (size_t)rc * 128 + q * 8;

        half8 av[4];
#pragma unroll
        for (int ks = 0; ks < 4; ks++) av[ks] = *(const half8*)(ap + ks * 32);
        {
            const int kb = t & 15;
            const int n0 = t >> 4;
#pragma unroll
            for (int it = 0; it < 4; it++) {
                const int n = n0 + it * 16;
                const uint4 v = *(const uint4*)(w2t + n * 128 + kb * 8);
                *(uint4*)((char*)lw + n * 256 + ((kb * 16) ^ ((n & 7) << 4))) = v;
            }
        }
        __syncthreads();

        floatx4 acc[4];
#pragma unroll
        for (int nt = 0; nt < 4; nt++) acc[nt] = (floatx4){0.f, 0.f, 0.f, 0.f};
        const int swz = (m & 7) << 4;
#pragma unroll
        for (int ks = 0; ks < 4; ks++) {
#pragma unroll
            for (int nt = 0; nt < 4; nt++) {
                const int n = nt * 16 + m;
                const half8 b = *(const half8*)((const char*)lw + n * 256 +
                                                ((ks * 64 + q * 16) ^ swz));
                acc[nt] = __builtin_amdgcn_mfma_f32_16x16x32_f16(av[ks], b, acc[nt], 0, 0, 0);
            }
        }
        __syncthreads();                          // lw reads done; alias as hs
        _Float16* hs = (_Float16*)smem;           // 8KB
        const int lrow0 = wv * 16 + q * 4;
#pragma unroll
        for (int nt = 0; nt < 4; nt++)
#pragma unroll
            for (int r = 0; r < 4; r++)
                hs[(lrow0 + r) * 64 + nt * 16 + m] = (_Float16)acc[nt][r];
        __syncthreads();

#pragma unroll
        for (int i = t; i < 512; i += 256) {
            const int row = i >> 3;
            if (gr0 + row < NN)
                ((half8*)h2h)[(size_t)(gr0 + row) * 8 + (i & 7)] = ((const half8*)hs)[i];
        }
        const int arow = t >> 2, sg = t & 3;
        const int grow = gr0 + arow;
        float ps = 0.f, pd = 0.f;
        const half8*  hp8 = (const half8*)(hs + arow * 64 + sg * 16);
        const float4* s4  = (const float4*)(at_s2 + sg * 16);
        const float4* d4  = (const float4*)(at_d2 + sg * 16);
#pragma unroll
        for (int cc = 0; cc < 2; cc++) {
            const half8 hv = hp8[cc];
            const float4 a = s4[cc * 2], b = s4[cc * 2 + 1];
            const float4 c = d4[cc * 2], e = d4[cc * 2 + 1];
            ps += (float)hv[0]*a.x + (float)hv[1]*a.y + (float)hv[2]*a.z + (float)hv[3]*a.w
                + (float)hv[4]*b.x + (float)hv[5]*b.y + (float)hv[6]*b.z + (float)hv[7]*b.w;
            pd += (float)hv[0]*c.x + (float)hv[1]*c.y + (float)hv[2]*c.z + (float)hv[3]*c.w
                + (float)hv[4]*e.x + (float)hv[5]*e.y + (float)hv[6]*e.z + (float)hv[7]*e.w;
        }
        ps += __shfl_down(ps, 2);  pd += __shfl_down(pd, 2);
        ps += __shfl_down(ps, 1);  pd += __shfl_down(pd, 1);
        if (sg == 0 && grow < NN) { as2[grow] = ps; ad2[grow] = pd; }
        __syncthreads();   // LDS reuse across tiles
    }
    gridbar(bar, nb);

    // ================= P5: agg2 (grid-stride node groups) =================
    {
        float* wbuf = (float*)smem;               // 4 waves x 64 floats
        float* wb = wbuf + wv * 64;
        for (int vb = bid; vb < NGRP; vb += nb) {
            const int d = __builtin_amdgcn_readfirstlane(vb * 4 + wv);
            const int beg = row_beg[d], end = row_end[d];
            const float add = ad2[d];
            float acc = 0.f, den = 0.f;

            for (int jb = beg; jb < end; jb += 64) {
                const int cnt = min(64, end - jb);
                {
                    const int sl = col[jb + min(lane, cnt - 1)];
                    wb[lane] = __expf(lrelu(as2[sl] + add));
                }
                __asm__ volatile("s_waitcnt lgkmcnt(0)" ::: "memory");

                int k = 0;
                for (; k + 16 <= cnt; k += 16) {
                    float w[16], g[16];
#pragma unroll
                    for (int u = 0; u < 16; u++) {
                        const int s = col[jb + k + u];
                        w[u] = wb[k + u];
                        g[u] = (float)h2h[s * 64 + lane];
                    }
#pragma unroll
                    for (int u = 0; u < 16; u++) {
                        den += w[u];
                        acc += w[u] * g[u];
                    }
                }
                for (; k + 4 <= cnt; k += 4) {
                    float w[4], g[4];
#pragma unroll
                    for (int u = 0; u < 4; u++) {
                        const int s = col[jb + k + u];
                        w[u] = wb[k + u];
                        g[u] = (float)h2h[s * 64 + lane];
                    }
#pragma unroll
                    for (int u = 0; u < 4; u++) {
                        den += w[u];
                        acc += w[u] * g[u];
                    }
                }
                for (; k < cnt; k++) {
                    const float w = wb[k];
                    den += w;
                    acc += w * (float)h2h[col[jb + k] * 64 + lane];
                }
                __asm__ volatile("" ::: "memory");
            }
            out[d * 64 + lane] = acc / (den + 1e-16f) + b2[lane];
        }
    }
}

// ---------------------------------------------------------------------------
extern "C" void kernel_launch(void* const* d_in, const int* in_sizes, int n_in,
                              void* d_out, int out_size, void* d_ws, size_t ws_size,
                              hipStream_t stream)
{
    const float* x    = (const float*)d_in[0];
    const int*   ei   = (const int*)  d_in[1];
    const float* W1   = (const float*)d_in[2];
    const float* at_s1= (const float*)d_in[3];
    const float* at_d1= (const float*)d_in[4];
    const float* b1   = (const float*)d_in[5];
    const float* W2   = (const float*)d_in[6];
    const float* at_s2= (const float*)d_in[7];
    const float* at_d2= (const float*)d_in[8];
    const float* b2   = (const float*)d_in[9];
    float*       out  = (float*)d_out;

    const size_t NPAD = (size_t)NBUCK * MAXB;

    // workspace layout (~48 MB)
    float* fw   = (float*)d_ws;
    float* as1  = fw;                  // NN*4
    float* ad1  = as1  + NN * 4;       // NN*4
    float* as2  = ad1  + NN * 4;       // NN
    float* ad2  = as2  + NN;           // NN
    _Float16* h1h   = (_Float16*)(ad2 + NN);   // NN*128
    _Float16* act1h = h1h  + (size_t)NN * 128; // NN*128
    _Float16* h2h   = act1h+ (size_t)NN * 128; // NN*64
    _Float16* w1t   = h2h  + (size_t)NN * 64;  // 16384
    _Float16* w2t   = w1t  + 16384;            // 8192
    int*   row_beg = (int*)(w2t + 8192);       // NN
    int*   row_end = row_beg + NN;             // NN
    int*   col     = row_end + NN;             // NPAD
    int*   bcnt    = col + NPAD;               // 4096 ints (stride-16 padded)
    unsigned* pairs = (unsigned*)(bcnt + 4096); // NPAD
    int*   bar     = (int*)(pairs + NPAD);     // 32 ints (2 cache lines)

    hipMemsetAsync(bar, 0, 32 * sizeof(int), stream);

    fused_gat_kernel<<<GRID, 256, 0, stream>>>(
        x, ei, W1, W2, at_s1, at_d1, b1, at_s2, at_d2, b2,
        w1t, w2t, bcnt, pairs, row_beg, row_end, col,
        as1, ad1, as2, ad2, h1h, act1h, h2h, out, bar);
}

// Round 7
// 549.584 us; speedup vs baseline: 1.8455x; 1.8455x over previous
//
#include <hip/hip_runtime.h>

#define NN    50000      // nodes
#define NE    800000     // edges (without self loops)
#define NET   850000     // NE + NN (with self loops)
#define NBUCK 196        // dst-buckets of 256 nodes
#define MAXB  8192       // padded slots per bucket
#define GRID  768        // 3 blocks/CU x 256 CUs — co-resident by construction
#define GTILE 782        // (NN+63)/64 gemm row-tiles
#define NGRP  12500      // NN/4 agg node-groups (4 nodes = 4 waves per group)

typedef __fp16 half2_t __attribute__((ext_vector_type(2)));
typedef _Float16 half8 __attribute__((ext_vector_type(8)));
typedef float floatx4 __attribute__((ext_vector_type(4)));

__device__ __forceinline__ float lrelu(float v) { return fmaxf(v, 0.2f * v); }
__device__ __forceinline__ unsigned pk16(float a, float b) {
    half2_t h = __builtin_amdgcn_cvt_pkrtz(a, b);
    return __builtin_bit_cast(unsigned, h);
}
__device__ __forceinline__ float2 unpk16(unsigned u) {
    half2_t h = __builtin_bit_cast(half2_t, u);
    return make_float2((float)h.x, (float)h.y);
}

// Device-scope grid barrier, R15 protocol:
//  - RELAXED spin (no per-poll cache invalidate — R6's ACQUIRE spin emitted
//    buffer_inv per poll and thrashed every XCD's L2 under the stragglers)
//  - one RELEASE fence (wbl2) before arrival, one ACQUIRE fence (inv) after
//    the wait — exactly one cache-maintenance pair per block per barrier.
//  - gen++ is RELEASE so the count reset can't wipe a next-barrier arrival.
// bar[0]=arrival, bar[16]=generation (separate 64B lines).
__device__ __forceinline__ void gridbar(int* bar, int nb) {
    __syncthreads();
    if (threadIdx.x == 0) {
        __builtin_amdgcn_fence(__ATOMIC_RELEASE, "agent");   // publish our stores
        const int gen = __hip_atomic_load(bar + 16, __ATOMIC_RELAXED, __HIP_MEMORY_SCOPE_AGENT);
        const int arr = __hip_atomic_fetch_add(bar, 1, __ATOMIC_RELAXED, __HIP_MEMORY_SCOPE_AGENT);
        if (arr == nb - 1) {
            __hip_atomic_store(bar, 0, __ATOMIC_RELAXED, __HIP_MEMORY_SCOPE_AGENT);
            __hip_atomic_fetch_add(bar + 16, 1, __ATOMIC_RELEASE, __HIP_MEMORY_SCOPE_AGENT);
        } else {
            int spins = 0;
            while (__hip_atomic_load(bar + 16, __ATOMIC_RELAXED, __HIP_MEMORY_SCOPE_AGENT) == gen) {
                __builtin_amdgcn_s_sleep(32);
                if (++spins > (1 << 16)) break;   // failsafe: fail visibly, never hang
            }
        }
        __builtin_amdgcn_fence(__ATOMIC_ACQUIRE, "agent");   // see others' stores
    }
    __syncthreads();
}

// ---------------------------------------------------------------------------
// Fused GAT pipeline, one launch:
//   P1 wprep+bin -> B1 -> P2 bsort||gemm1 -> B2 -> P3 agg1 -> B3
//   -> P4 gemm2 -> B4 -> P5 agg2
// ---------------------------------------------------------------------------
__global__ __launch_bounds__(256, 3) void fused_gat_kernel(
    const float* __restrict__ x, const int* __restrict__ ei,
    const float* __restrict__ W1, const float* __restrict__ W2,
    const float* __restrict__ at_s1, const float* __restrict__ at_d1,
    const float* __restrict__ b1,
    const float* __restrict__ at_s2, const float* __restrict__ at_d2,
    const float* __restrict__ b2,
    _Float16* __restrict__ w1t, _Float16* __restrict__ w2t,
    int* __restrict__ bcnt, unsigned* __restrict__ pairs,
    int* __restrict__ row_beg, int* __restrict__ row_end, int* __restrict__ col,
    float* __restrict__ as1, float* __restrict__ ad1,
    float* __restrict__ as2, float* __restrict__ ad2,
    _Float16* __restrict__ h1h, _Float16* __restrict__ act1h,
    _Float16* __restrict__ h2h, float* __restrict__ out,
    int* __restrict__ bar)
{
    __shared__ __align__(16) char smem[35840];   // max over phases (bsort 35KB)
    const int t    = threadIdx.x;
    const int bid  = blockIdx.x;
    const int nb   = gridDim.x;
    const int lane = t & 63;
    const int wv   = t >> 6;

    // ================= P1: folded weight prep + bin =======================
    // (bcnt zeroed by host memset, stream-ordered before this kernel)
    for (int idx = bid * 256 + t; idx < 24576; idx += nb * 256) {
        if (idx < 16384) {
            w1t[(idx & 127) * 128 + (idx >> 7)] = (_Float16)W1[idx];
        } else {
            const int j = idx - 16384;
            w2t[(j & 63) * 128 + (j >> 6)] = (_Float16)W2[j];
        }
    }
    {
        int* hist = (int*)smem;
        int* base = hist + NBUCK;
        int* cur  = base + NBUCK;
        if (t < NBUCK) { hist[t] = 0; cur[t] = 0; }
        __syncthreads();
        for (int e = bid * 256 + t; e < NET; e += nb * 256) {
            const int d = (e < NE) ? ei[NE + e] : (e - NE);
            atomicAdd(&hist[d >> 8], 1);
        }
        __syncthreads();
        if (t < NBUCK && hist[t]) base[t] = atomicAdd(&bcnt[t * 16], hist[t]);
        __syncthreads();
        for (int e = bid * 256 + t; e < NET; e += nb * 256) {
            int s, d;
            if (e < NE) { s = ei[e]; d = ei[NE + e]; } else { s = d = e - NE; }
            const int bk = d >> 8;
            const int r = atomicAdd(&cur[bk], 1);
            pairs[(size_t)bk * MAXB + base[bk] + r] =
                (unsigned)s | ((unsigned)(d & 255) << 16);
        }
    }
    gridbar(bar, nb);

    // ================= P2: bsort (vt<NBUCK) || gemm1 (else) ===============
    for (int vt = bid; vt < NBUCK + GTILE; vt += nb) {
        if (vt < NBUCK) {
            const int b = vt;
            int* hist = (int*)smem;
            int* cur  = hist + 256;
            int* sh   = cur + 256;
            int* outl = sh + 256;                 // MAXB ints = 32KB
            const int m = bcnt[b * 16];
            const int gbase = b * MAXB;
            hist[t] = 0;
            __syncthreads();
            for (int i = t; i < m; i += 256)
                atomicAdd(&hist[pairs[gbase + i] >> 16], 1);
            __syncthreads();
            sh[t] = hist[t];
            __syncthreads();
#pragma unroll
            for (int off = 1; off < 256; off <<= 1) {
                const int u = (t >= off) ? sh[t - off] : 0;
                __syncthreads();
                sh[t] += u;
                __syncthreads();
            }
            {
                const int ex = sh[t] - hist[t];
                cur[t] = ex;
                const int node = (b << 8) + t;
                if (node < NN) {
                    row_beg[node] = gbase + ex;
                    row_end[node] = gbase + ex + hist[t];
                }
            }
            __syncthreads();
            for (int i = t; i < m; i += 256) {
                const unsigned p = pairs[gbase + i];
                const int r = atomicAdd(&cur[p >> 16], 1);
                outl[r] = (int)(p & 0xFFFFu);
            }
            __syncthreads();
            for (int i = t; i < m; i += 256) col[gbase + i] = outl[i];
        } else {
            // ---- gemm1 tile (R13 internals, LDS lw->hs aliased) ----
            const int tile = vt - NBUCK;
            _Float16* lw = (_Float16*)smem;       // 32KB swizzled W1^T
            const int m  = lane & 15;
            const int q  = lane >> 4;
            const int gr0 = tile * 64;
            const int rme = gr0 + wv * 16 + m;
            const int rc  = rme < NN ? rme : NN - 1;
            const float* ap = x + (size_t)rc * 128 + q * 8;

            float4 f0[4], f1[4];
#pragma unroll
            for (int ks = 0; ks < 4; ks++) {
                f0[ks] = *(const float4*)(ap + ks * 32);
                f1[ks] = *(const float4*)(ap + ks * 32 + 4);
            }
            {
                const int kb = t & 15;
                const int n0 = t >> 4;
#pragma unroll
                for (int it = 0; it < 8; it++) {
                    const int n = n0 + it * 16;
                    const uint4 v = *(const uint4*)(w1t + n * 128 + kb * 8);
                    *(uint4*)((char*)lw + n * 256 + ((kb * 16) ^ ((n & 7) << 4))) = v;
                }
            }
            __syncthreads();

            floatx4 acc[8];
#pragma unroll
            for (int nt = 0; nt < 8; nt++) acc[nt] = (floatx4){0.f, 0.f, 0.f, 0.f};
            const int swz = (m & 7) << 4;
#pragma unroll
            for (int ks = 0; ks < 4; ks++) {
                const uint4 au = make_uint4(pk16(f0[ks].x, f0[ks].y), pk16(f0[ks].z, f0[ks].w),
                                            pk16(f1[ks].x, f1[ks].y), pk16(f1[ks].z, f1[ks].w));
                const half8 a = __builtin_bit_cast(half8, au);
#pragma unroll
                for (int nt = 0; nt < 8; nt++) {
                    const int n = nt * 16 + m;
                    const half8 b = *(const half8*)((const char*)lw + n * 256 +
                                                    ((ks * 64 + q * 16) ^ swz));
                    acc[nt] = __builtin_amdgcn_mfma_f32_16x16x32_f16(a, b, acc[nt], 0, 0, 0);
                }
            }
            __syncthreads();                      // lw reads done; alias as hs
            _Float16* hs = (_Float16*)smem;       // 16KB
            const int lrow0 = wv * 16 + q * 4;
#pragma unroll
            for (int nt = 0; nt < 8; nt++)
#pragma unroll
                for (int r = 0; r < 4; r++)
                    hs[(lrow0 + r) * 128 + nt * 16 + m] = (_Float16)acc[nt][r];
            __syncthreads();

#pragma unroll
            for (int i = t; i < 1024; i += 256) {
                const int row = i >> 4;
                if (gr0 + row < NN)
                    ((half8*)h1h)[(size_t)(gr0 + row) * 16 + (i & 15)] = ((const half8*)hs)[i];
            }
            const int arow = t >> 2, hd = t & 3;
            const int grow = gr0 + arow;
            float ps = 0.f, pd = 0.f;
            const half8*  hp8 = (const half8*)(hs + arow * 128 + hd * 32);
            const float4* s4  = (const float4*)(at_s1 + hd * 32);
            const float4* d4  = (const float4*)(at_d1 + hd * 32);
#pragma unroll
            for (int cc = 0; cc < 4; cc++) {
                const half8 hv = hp8[cc];
                const float4 a = s4[cc * 2], b = s4[cc * 2 + 1];
                const float4 c = d4[cc * 2], e = d4[cc * 2 + 1];
                ps += (float)hv[0]*a.x + (float)hv[1]*a.y + (float)hv[2]*a.z + (float)hv[3]*a.w
                    + (float)hv[4]*b.x + (float)hv[5]*b.y + (float)hv[6]*b.z + (float)hv[7]*b.w;
                pd += (float)hv[0]*c.x + (float)hv[1]*c.y + (float)hv[2]*c.z + (float)hv[3]*c.w
                    + (float)hv[4]*e.x + (float)hv[5]*e.y + (float)hv[6]*e.z + (float)hv[7]*e.w;
            }
            if (grow < NN) {
                as1[grow * 4 + hd] = ps;
                ad1[grow * 4 + hd] = pd;
            }
        }
        __syncthreads();   // LDS reuse across vt tasks
    }
    gridbar(bar, nb);

    // ================= P3: agg1 (grid-stride node groups) =================
    {
        float* wbuf = (float*)smem;               // 4 waves x 256 floats
        const int head = lane >> 4;
        float* wb = wbuf + wv * 256;
        for (int vb = bid; vb < NGRP; vb += nb) {
            const int d = __builtin_amdgcn_readfirstlane(vb * 4 + wv);
            const int beg = row_beg[d], end = row_end[d];
            const float4 ad4 = ((const float4*)ad1)[d];
            float acc0 = 0.f, acc1 = 0.f, den = 0.f;

            for (int jb = beg; jb < end; jb += 64) {
                const int cnt = min(64, end - jb);
                {
                    const int sl = col[jb + min(lane, cnt - 1)];
                    const float4 a = ((const float4*)as1)[sl];
                    float4 w4;
                    w4.x = __expf(lrelu(a.x + ad4.x));
                    w4.y = __expf(lrelu(a.y + ad4.y));
                    w4.z = __expf(lrelu(a.z + ad4.z));
                    w4.w = __expf(lrelu(a.w + ad4.w));
                    ((float4*)wb)[lane] = w4;
                }
                __asm__ volatile("s_waitcnt lgkmcnt(0)" ::: "memory");

                const unsigned* hh = (const unsigned*)h1h;
                int k = 0;
                for (; k + 16 <= cnt; k += 16) {
                    float    w[16];
                    unsigned g[16];
#pragma unroll
                    for (int u = 0; u < 16; u++) {
                        const int s = col[jb + k + u];
                        w[u] = wb[(k + u) * 4 + head];
                        g[u] = hh[s * 64 + lane];
                    }
#pragma unroll
                    for (int u = 0; u < 16; u++) {
                        const float2 g2 = unpk16(g[u]);
                        den  += w[u];
                        acc0 += w[u] * g2.x;
                        acc1 += w[u] * g2.y;
                    }
                }
                for (; k + 4 <= cnt; k += 4) {
                    float    w[4];
                    unsigned g[4];
#pragma unroll
                    for (int u = 0; u < 4; u++) {
                        const int s = col[jb + k + u];
                        w[u] = wb[(k + u) * 4 + head];
                        g[u] = hh[s * 64 + lane];
                    }
#pragma unroll
                    for (int u = 0; u < 4; u++) {
                        const float2 g2 = unpk16(g[u]);
                        den  += w[u];
                        acc0 += w[u] * g2.x;
                        acc1 += w[u] * g2.y;
                    }
                }
                for (; k < cnt; k++) {
                    const float w = wb[k * 4 + head];
                    const float2 g2 = unpk16(hh[col[jb + k] * 64 + lane]);
                    den  += w;
                    acc0 += w * g2.x;
                    acc1 += w * g2.y;
                }
                __asm__ volatile("" ::: "memory");
            }
            const float2 bb  = ((const float2*)b1)[lane];
            const float  inv = 1.f / (den + 1e-16f);
            float v0 = acc0 * inv + bb.x;
            float v1 = acc1 * inv + bb.y;
            v0 = v0 > 0.f ? v0 : (__expf(v0) - 1.f);
            v1 = v1 > 0.f ? v1 : (__expf(v1) - 1.f);
            ((unsigned*)act1h)[d * 64 + lane] = pk16(v0, v1);
        }
    }
    gridbar(bar, nb);

    // ================= P4: gemm2 (grid-stride tiles) ======================
    for (int tile = bid; tile < GTILE; tile += nb) {
        _Float16* lw = (_Float16*)smem;           // 16KB swizzled W2^T
        const int m  = lane & 15;
        const int q  = lane >> 4;
        const int gr0 = tile * 64;
        const int rme = gr0 + wv * 16 + m;
        const int rc  = rme < NN ? rme : NN - 1;
        const _Float16* ap = act1h + (size_t)rc * 128 + q * 8;

        half8 av[4];
#pragma unroll
        for (int ks = 0; ks < 4; ks++) av[ks] = *(const half8*)(ap + ks * 32);
        {
            const int kb = t & 15;
            const int n0 = t >> 4;
#pragma unroll
            for (int it = 0; it < 4; it++) {
                const int n = n0 + it * 16;
                const uint4 v = *(const uint4*)(w2t + n * 128 + kb * 8);
                *(uint4*)((char*)lw + n * 256 + ((kb * 16) ^ ((n & 7) << 4))) = v;
            }
        }
        __syncthreads();

        floatx4 acc[4];
#pragma unroll
        for (int nt = 0; nt < 4; nt++) acc[nt] = (floatx4){0.f, 0.f, 0.f, 0.f};
        const int swz = (m & 7) << 4;
#pragma unroll
        for (int ks = 0; ks < 4; ks++) {
#pragma unroll
            for (int nt = 0; nt < 4; nt++) {
                const int n = nt * 16 + m;
                const half8 b = *(const half8*)((const char*)lw + n * 256 +
                                                ((ks * 64 + q * 16) ^ swz));
                acc[nt] = __builtin_amdgcn_mfma_f32_16x16x32_f16(av[ks], b, acc[nt], 0, 0, 0);
            }
        }
        __syncthreads();                          // lw reads done; alias as hs
        _Float16* hs = (_Float16*)smem;           // 8KB
        const int lrow0 = wv * 16 + q * 4;
#pragma unroll
        for (int nt = 0; nt < 4; nt++)
#pragma unroll
            for (int r = 0; r < 4; r++)
                hs[(lrow0 + r) * 64 + nt * 16 + m] = (_Float16)acc[nt][r];
        __syncthreads();

#pragma unroll
        for (int i = t; i < 512; i += 256) {
            const int row = i >> 3;
            if (gr0 + row < NN)
                ((half8*)h2h)[(size_t)(gr0 + row) * 8 + (i & 7)] = ((const half8*)hs)[i];
        }
        const int arow = t >> 2, sg = t & 3;
        const int grow = gr0 + arow;
        float ps = 0.f, pd = 0.f;
        const half8*  hp8 = (const half8*)(hs + arow * 64 + sg * 16);
        const float4* s4  = (const float4*)(at_s2 + sg * 16);
        const float4* d4  = (const float4*)(at_d2 + sg * 16);
#pragma unroll
        for (int cc = 0; cc < 2; cc++) {
            const half8 hv = hp8[cc];
            const float4 a = s4[cc * 2], b = s4[cc * 2 + 1];
            const float4 c = d4[cc * 2], e = d4[cc * 2 + 1];
            ps += (float)hv[0]*a.x + (float)hv[1]*a.y + (float)hv[2]*a.z + (float)hv[3]*a.w
                + (float)hv[4]*b.x + (float)hv[5]*b.y + (float)hv[6]*b.z + (float)hv[7]*b.w;
            pd += (float)hv[0]*c.x + (float)hv[1]*c.y + (float)hv[2]*c.z + (float)hv[3]*c.w
                + (float)hv[4]*e.x + (float)hv[5]*e.y + (float)hv[6]*e.z + (float)hv[7]*e.w;
        }
        ps += __shfl_down(ps, 2);  pd += __shfl_down(pd, 2);
        ps += __shfl_down(ps, 1);  pd += __shfl_down(pd, 1);
        if (sg == 0 && grow < NN) { as2[grow] = ps; ad2[grow] = pd; }
        __syncthreads();   // LDS reuse across tiles
    }
    gridbar(bar, nb);

    // ================= P5: agg2 (grid-stride node groups) =================
    {
        float* wbuf = (float*)smem;               // 4 waves x 64 floats
        float* wb = wbuf + wv * 64;
        for (int vb = bid; vb < NGRP; vb += nb) {
            const int d = __builtin_amdgcn_readfirstlane(vb * 4 + wv);
            const int beg = row_beg[d], end = row_end[d];
            const float add = ad2[d];
            float acc = 0.f, den = 0.f;

            for (int jb = beg; jb < end; jb += 64) {
                const int cnt = min(64, end - jb);
                {
                    const int sl = col[jb + min(lane, cnt - 1)];
                    wb[lane] = __expf(lrelu(as2[sl] + add));
                }
                __asm__ volatile("s_waitcnt lgkmcnt(0)" ::: "memory");

                int k = 0;
                for (; k + 16 <= cnt; k += 16) {
                    float w[16], g[16];
#pragma unroll
                    for (int u = 0; u < 16; u++) {
                        const int s = col[jb + k + u];
                        w[u] = wb[k + u];
                        g[u] = (float)h2h[s * 64 + lane];
                    }
#pragma unroll
                    for (int u = 0; u < 16; u++) {
                        den += w[u];
                        acc += w[u] * g[u];
                    }
                }
                for (; k + 4 <= cnt; k += 4) {
                    float w[4], g[4];
#pragma unroll
                    for (int u = 0; u < 4; u++) {
                        const int s = col[jb + k + u];
                        w[u] = wb[k + u];
                        g[u] = (float)h2h[s * 64 + lane];
                    }
#pragma unroll
                    for (int u = 0; u < 4; u++) {
                        den += w[u];
                        acc += w[u] * g[u];
                    }
                }
                for (; k < cnt; k++) {
                    const float w = wb[k];
                    den += w;
                    acc += w * (float)h2h[col[jb + k] * 64 + lane];
                }
                __asm__ volatile("" ::: "memory");
            }
            out[d * 64 + lane] = acc / (den + 1e-16f) + b2[lane];
        }
    }
}

// ---------------------------------------------------------------------------
extern "C" void kernel_launch(void* const* d_in, const int* in_sizes, int n_in,
                              void* d_out, int out_size, void* d_ws, size_t ws_size,
                              hipStream_t stream)
{
    const float* x    = (const float*)d_in[0];
    const int*   ei   = (const int*)  d_in[1];
    const float* W1   = (const float*)d_in[2];
    const float* at_s1= (const float*)d_in[3];
    const float* at_d1= (const float*)d_in[4];
    const float* b1   = (const float*)d_in[5];
    const float* W2   = (const float*)d_in[6];
    const float* at_s2= (const float*)d_in[7];
    const float* at_d2= (const float*)d_in[8];
    const float* b2   = (const float*)d_in[9];
    float*       out  = (float*)d_out;

    const size_t NPAD = (size_t)NBUCK * MAXB;

    // workspace layout (~48 MB); bcnt+bar contiguous for ONE memset
    float* fw   = (float*)d_ws;
    float* as1  = fw;                  // NN*4
    float* ad1  = as1  + NN * 4;       // NN*4
    float* as2  = ad1  + NN * 4;       // NN
    float* ad2  = as2  + NN;           // NN
    _Float16* h1h   = (_Float16*)(ad2 + NN);   // NN*128
    _Float16* act1h = h1h  + (size_t)NN * 128; // NN*128
    _Float16* h2h   = act1h+ (size_t)NN * 128; // NN*64
    _Float16* w1t   = h2h  + (size_t)NN * 64;  // 16384
    _Float16* w2t   = w1t  + 16384;            // 8192
    int*   row_beg = (int*)(w2t + 8192);       // NN
    int*   row_end = row_beg + NN;             // NN
    int*   col     = row_end + NN;             // NPAD
    int*   bcnt    = col + NPAD;               // 4096 ints (stride-16 padded)
    int*   bar     = bcnt + 4096;              // 32 ints (2 cache lines)
    unsigned* pairs = (unsigned*)(bar + 32);   // NPAD

    hipMemsetAsync(bcnt, 0, (4096 + 32) * sizeof(int), stream);

    fused_gat_kernel<<<GRID, 256, 0, stream>>>(
        x, ei, W1, W2, at_s1, at_d1, b1, at_s2, at_d2, b2,
        w1t, w2t, bcnt, pairs, row_beg, row_end, col,
        as1, ad1, as2, ad2, h1h, act1h, h2h, out, bar);
}

// Round 8
// 368.487 us; speedup vs baseline: 2.7526x; 1.4915x over previous
//
#include <hip/hip_runtime.h>

#define NN    50000      // nodes
#define NE    800000     // edges (without self loops)
#define NET   850000     // NE + NN (with self loops)
#define NBUCK 196        // dst-buckets of 256 nodes
#define MAXB  8192       // padded slots per bucket
#define GRID  1024       // 4 blocks/CU x 256 CUs — co-resident by construction
#define GTILE 782        // (NN+63)/64 gemm row-tiles
#define NGRP  12500      // NN/4 agg node-groups (4 nodes = 4 waves per group)

typedef __fp16 half2_t __attribute__((ext_vector_type(2)));
typedef _Float16 half8 __attribute__((ext_vector_type(8)));
typedef float floatx4 __attribute__((ext_vector_type(4)));

__device__ __forceinline__ float lrelu(float v) { return fmaxf(v, 0.2f * v); }
__device__ __forceinline__ unsigned pk16(float a, float b) {
    half2_t h = __builtin_amdgcn_cvt_pkrtz(a, b);
    return __builtin_bit_cast(unsigned, h);
}
__device__ __forceinline__ float2 unpk16(unsigned u) {
    half2_t h = __builtin_bit_cast(half2_t, u);
    return make_float2((float)h.x, (float)h.y);
}

// Slot-based grid barrier (R16). R7's counter barrier serialized 768
// same-line fetch_adds through the fabric (~130ns each = ~100us/barrier).
// Here: arrival = STORE to own slot (distinct lines, fully parallel);
// block 0 sweeps slots with 256 threads and release-stores gen; members
// spin on relaxed gen loads (read-only, no line ping-pong). Monotonic
// phase numbers — no reset, no ABA. Failsafe break: fail visibly, no hang.
__device__ __forceinline__ void gridbar(int* slots, int* genp, int phase, int nb) {
    __syncthreads();
    const int t = threadIdx.x;
    if (blockIdx.x == 0) {
        __shared__ int wok[4];
        if (t == 0) {
            __builtin_amdgcn_fence(__ATOMIC_RELEASE, "agent");
            __hip_atomic_store(&slots[0], phase, __ATOMIC_RELAXED, __HIP_MEMORY_SCOPE_AGENT);
        }
        __syncthreads();
        int spins = 0;
        for (;;) {
            int ok = 1;
            for (int i = t; i < nb; i += 256)
                ok &= (__hip_atomic_load(&slots[i], __ATOMIC_RELAXED, __HIP_MEMORY_SCOPE_AGENT) >= phase);
            ok = __all(ok) ? 1 : 0;
            if ((t & 63) == 0) wok[t >> 6] = ok;
            __syncthreads();
            const int alldone = wok[0] & wok[1] & wok[2] & wok[3];
            __syncthreads();            // protect wok before next-iter write
            if (alldone) break;
            if (++spins > (1 << 14)) break;     // failsafe
            __builtin_amdgcn_s_sleep(1);
        }
        if (t == 0) {
            __builtin_amdgcn_fence(__ATOMIC_ACQUIRE, "agent");  // transitivity
            __hip_atomic_store(genp, phase, __ATOMIC_RELEASE, __HIP_MEMORY_SCOPE_AGENT);
        }
    } else {
        if (t == 0) {
            __builtin_amdgcn_fence(__ATOMIC_RELEASE, "agent");
            __hip_atomic_store(&slots[blockIdx.x], phase, __ATOMIC_RELAXED, __HIP_MEMORY_SCOPE_AGENT);
            int spins = 0;
            while (__hip_atomic_load(genp, __ATOMIC_RELAXED, __HIP_MEMORY_SCOPE_AGENT) < phase) {
                __builtin_amdgcn_s_sleep(8);
                if (++spins > (1 << 16)) break; // failsafe
            }
            __builtin_amdgcn_fence(__ATOMIC_ACQUIRE, "agent");
        }
    }
    __syncthreads();
}

// ---------------------------------------------------------------------------
// Fused GAT pipeline, one launch:
//   P1 wprep+bin -> B1 -> P2 bsort||gemm1 -> B2 -> P3 agg1 -> B3
//   -> P4 gemm2 -> B4 -> P5 agg2
// ---------------------------------------------------------------------------
__global__ __launch_bounds__(256, 4) void fused_gat_kernel(
    const float* __restrict__ x, const int* __restrict__ ei,
    const float* __restrict__ W1, const float* __restrict__ W2,
    const float* __restrict__ at_s1, const float* __restrict__ at_d1,
    const float* __restrict__ b1,
    const float* __restrict__ at_s2, const float* __restrict__ at_d2,
    const float* __restrict__ b2,
    _Float16* __restrict__ w1t, _Float16* __restrict__ w2t,
    int* __restrict__ bcnt, unsigned* __restrict__ pairs,
    int* __restrict__ row_beg, int* __restrict__ row_end, int* __restrict__ col,
    float* __restrict__ as1, float* __restrict__ ad1,
    float* __restrict__ as2, float* __restrict__ ad2,
    _Float16* __restrict__ h1h, _Float16* __restrict__ act1h,
    _Float16* __restrict__ h2h, float* __restrict__ out,
    int* __restrict__ genp, int* __restrict__ slots)
{
    __shared__ __align__(16) char smem[35840];   // max over phases (bsort 35KB)
    const int t    = threadIdx.x;
    const int bid  = blockIdx.x;
    const int nb   = gridDim.x;
    const int lane = t & 63;
    const int wv   = t >> 6;

    // ================= P1: folded weight prep + bin =======================
    // (bcnt + slots + gen zeroed by host memset, stream-ordered before us)
    for (int idx = bid * 256 + t; idx < 24576; idx += nb * 256) {
        if (idx < 16384) {
            w1t[(idx & 127) * 128 + (idx >> 7)] = (_Float16)W1[idx];
        } else {
            const int j = idx - 16384;
            w2t[(j & 63) * 128 + (j >> 6)] = (_Float16)W2[j];
        }
    }
    {
        int* hist = (int*)smem;
        int* base = hist + NBUCK;
        int* cur  = base + NBUCK;
        if (t < NBUCK) { hist[t] = 0; cur[t] = 0; }
        __syncthreads();
        for (int e = bid * 256 + t; e < NET; e += nb * 256) {
            const int d = (e < NE) ? ei[NE + e] : (e - NE);
            atomicAdd(&hist[d >> 8], 1);
        }
        __syncthreads();
        if (t < NBUCK && hist[t]) base[t] = atomicAdd(&bcnt[t * 16], hist[t]);
        __syncthreads();
        for (int e = bid * 256 + t; e < NET; e += nb * 256) {
            int s, d;
            if (e < NE) { s = ei[e]; d = ei[NE + e]; } else { s = d = e - NE; }
            const int bk = d >> 8;
            const int r = atomicAdd(&cur[bk], 1);
            pairs[(size_t)bk * MAXB + base[bk] + r] =
                (unsigned)s | ((unsigned)(d & 255) << 16);
        }
    }
    gridbar(slots, genp, 1, nb);

    // ================= P2: bsort (vt<NBUCK) || gemm1 (else) ===============
    for (int vt = bid; vt < NBUCK + GTILE; vt += nb) {
        if (vt < NBUCK) {
            const int b = vt;
            int* hist = (int*)smem;
            int* cur  = hist + 256;
            int* sh   = cur + 256;
            int* outl = sh + 256;                 // MAXB ints = 32KB
            const int m = bcnt[b * 16];
            const int gbase = b * MAXB;
            hist[t] = 0;
            __syncthreads();
            for (int i = t; i < m; i += 256)
                atomicAdd(&hist[pairs[gbase + i] >> 16], 1);
            __syncthreads();
            sh[t] = hist[t];
            __syncthreads();
#pragma unroll
            for (int off = 1; off < 256; off <<= 1) {
                const int u = (t >= off) ? sh[t - off] : 0;
                __syncthreads();
                sh[t] += u;
                __syncthreads();
            }
            {
                const int ex = sh[t] - hist[t];
                cur[t] = ex;
                const int node = (b << 8) + t;
                if (node < NN) {
                    row_beg[node] = gbase + ex;
                    row_end[node] = gbase + ex + hist[t];
                }
            }
            __syncthreads();
            for (int i = t; i < m; i += 256) {
                const unsigned p = pairs[gbase + i];
                const int r = atomicAdd(&cur[p >> 16], 1);
                outl[r] = (int)(p & 0xFFFFu);
            }
            __syncthreads();
            for (int i = t; i < m; i += 256) col[gbase + i] = outl[i];
        } else {
            // ---- gemm1 tile (R13 internals, LDS lw->hs aliased) ----
            const int tile = vt - NBUCK;
            _Float16* lw = (_Float16*)smem;       // 32KB swizzled W1^T
            const int m  = lane & 15;
            const int q  = lane >> 4;
            const int gr0 = tile * 64;
            const int rme = gr0 + wv * 16 + m;
            const int rc  = rme < NN ? rme : NN - 1;
            const float* ap = x + (size_t)rc * 128 + q * 8;

            float4 f0[4], f1[4];
#pragma unroll
            for (int ks = 0; ks < 4; ks++) {
                f0[ks] = *(const float4*)(ap + ks * 32);
                f1[ks] = *(const float4*)(ap + ks * 32 + 4);
            }
            {
                const int kb = t & 15;
                const int n0 = t >> 4;
#pragma unroll
                for (int it = 0; it < 8; it++) {
                    const int n = n0 + it * 16;
                    const uint4 v = *(const uint4*)(w1t + n * 128 + kb * 8);
                    *(uint4*)((char*)lw + n * 256 + ((kb * 16) ^ ((n & 7) << 4))) = v;
                }
            }
            __syncthreads();

            floatx4 acc[8];
#pragma unroll
            for (int nt = 0; nt < 8; nt++) acc[nt] = (floatx4){0.f, 0.f, 0.f, 0.f};
            const int swz = (m & 7) << 4;
#pragma unroll
            for (int ks = 0; ks < 4; ks++) {
                const uint4 au = make_uint4(pk16(f0[ks].x, f0[ks].y), pk16(f0[ks].z, f0[ks].w),
                                            pk16(f1[ks].x, f1[ks].y), pk16(f1[ks].z, f1[ks].w));
                const half8 a = __builtin_bit_cast(half8, au);
#pragma unroll
                for (int nt = 0; nt < 8; nt++) {
                    const int n = nt * 16 + m;
                    const half8 b = *(const half8*)((const char*)lw + n * 256 +
                                                    ((ks * 64 + q * 16) ^ swz));
                    acc[nt] = __builtin_amdgcn_mfma_f32_16x16x32_f16(a, b, acc[nt], 0, 0, 0);
                }
            }
            __syncthreads();                      // lw reads done; alias as hs
            _Float16* hs = (_Float16*)smem;       // 16KB
            const int lrow0 = wv * 16 + q * 4;
#pragma unroll
            for (int nt = 0; nt < 8; nt++)
#pragma unroll
                for (int r = 0; r < 4; r++)
                    hs[(lrow0 + r) * 128 + nt * 16 + m] = (_Float16)acc[nt][r];
            __syncthreads();

#pragma unroll
            for (int i = t; i < 1024; i += 256) {
                const int row = i >> 4;
                if (gr0 + row < NN)
                    ((half8*)h1h)[(size_t)(gr0 + row) * 16 + (i & 15)] = ((const half8*)hs)[i];
            }
            const int arow = t >> 2, hd = t & 3;
            const int grow = gr0 + arow;
            float ps = 0.f, pd = 0.f;
            const half8*  hp8 = (const half8*)(hs + arow * 128 + hd * 32);
            const float4* s4  = (const float4*)(at_s1 + hd * 32);
            const float4* d4  = (const float4*)(at_d1 + hd * 32);
#pragma unroll
            for (int cc = 0; cc < 4; cc++) {
                const half8 hv = hp8[cc];
                const float4 a = s4[cc * 2], b = s4[cc * 2 + 1];
                const float4 c = d4[cc * 2], e = d4[cc * 2 + 1];
                ps += (float)hv[0]*a.x + (float)hv[1]*a.y + (float)hv[2]*a.z + (float)hv[3]*a.w
                    + (float)hv[4]*b.x + (float)hv[5]*b.y + (float)hv[6]*b.z + (float)hv[7]*b.w;
                pd += (float)hv[0]*c.x + (float)hv[1]*c.y + (float)hv[2]*c.z + (float)hv[3]*c.w
                    + (float)hv[4]*e.x + (float)hv[5]*e.y + (float)hv[6]*e.z + (float)hv[7]*e.w;
            }
            if (grow < NN) {
                as1[grow * 4 + hd] = ps;
                ad1[grow * 4 + hd] = pd;
            }
        }
        __syncthreads();   // LDS reuse across vt tasks
    }
    gridbar(slots, genp, 2, nb);

    // ================= P3: agg1 (grid-stride node groups) =================
    {
        float* wbuf = (float*)smem;               // 4 waves x 256 floats
        const int head = lane >> 4;
        float* wb = wbuf + wv * 256;
        for (int vb = bid; vb < NGRP; vb += nb) {
            const int d = __builtin_amdgcn_readfirstlane(vb * 4 + wv);
            const int beg = row_beg[d], end = row_end[d];
            const float4 ad4 = ((const float4*)ad1)[d];
            float acc0 = 0.f, acc1 = 0.f, den = 0.f;

            for (int jb = beg; jb < end; jb += 64) {
                const int cnt = min(64, end - jb);
                {
                    const int sl = col[jb + min(lane, cnt - 1)];
                    const float4 a = ((const float4*)as1)[sl];
                    float4 w4;
                    w4.x = __expf(lrelu(a.x + ad4.x));
                    w4.y = __expf(lrelu(a.y + ad4.y));
                    w4.z = __expf(lrelu(a.z + ad4.z));
                    w4.w = __expf(lrelu(a.w + ad4.w));
                    ((float4*)wb)[lane] = w4;
                }
                __asm__ volatile("s_waitcnt lgkmcnt(0)" ::: "memory");

                const unsigned* hh = (const unsigned*)h1h;
                int k = 0;
                for (; k + 16 <= cnt; k += 16) {
                    float    w[16];
                    unsigned g[16];
#pragma unroll
                    for (int u = 0; u < 16; u++) {
                        const int s = col[jb + k + u];
                        w[u] = wb[(k + u) * 4 + head];
                        g[u] = hh[s * 64 + lane];
                    }
#pragma unroll
                    for (int u = 0; u < 16; u++) {
                        const float2 g2 = unpk16(g[u]);
                        den  += w[u];
                        acc0 += w[u] * g2.x;
                        acc1 += w[u] * g2.y;
                    }
                }
                for (; k + 4 <= cnt; k += 4) {
                    float    w[4];
                    unsigned g[4];
#pragma unroll
                    for (int u = 0; u < 4; u++) {
                        const int s = col[jb + k + u];
                        w[u] = wb[(k + u) * 4 + head];
                        g[u] = hh[s * 64 + lane];
                    }
#pragma unroll
                    for (int u = 0; u < 4; u++) {
                        const float2 g2 = unpk16(g[u]);
                        den  += w[u];
                        acc0 += w[u] * g2.x;
                        acc1 += w[u] * g2.y;
                    }
                }
                for (; k < cnt; k++) {
                    const float w = wb[k * 4 + head];
                    const float2 g2 = unpk16(hh[col[jb + k] * 64 + lane]);
                    den  += w;
                    acc0 += w * g2.x;
                    acc1 += w * g2.y;
                }
                __asm__ volatile("" ::: "memory");
            }
            const float2 bb  = ((const float2*)b1)[lane];
            const float  inv = 1.f / (den + 1e-16f);
            float v0 = acc0 * inv + bb.x;
            float v1 = acc1 * inv + bb.y;
            v0 = v0 > 0.f ? v0 : (__expf(v0) - 1.f);
            v1 = v1 > 0.f ? v1 : (__expf(v1) - 1.f);
            ((unsigned*)act1h)[d * 64 + lane] = pk16(v0, v1);
        }
    }
    gridbar(slots, genp, 3, nb);

    // ================= P4: gemm2 (grid-stride tiles) ======================
    for (int tile = bid; tile < GTILE; tile += nb) {
        _Float16* lw = (_Float16*)smem;           // 16KB swizzled W2^T
        const int m  = lane & 15;
        const int q  = lane >> 4;
        const int gr0 = tile * 64;
        const int rme = gr0 + wv * 16 + m;
        const int rc  = rme < NN ? rme : NN - 1;
        const _Float16* ap = act1h + (size_t)rc * 128 + q * 8;

        half8 av[4];
#pragma unroll
        for (int ks = 0; ks < 4; ks++) av[ks] = *(const half8*)(ap + ks * 32);
        {
            const int kb = t & 15;
            const int n0 = t >> 4;
#pragma unroll
            for (int it = 0; it < 4; it++) {
                const int n = n0 + it * 16;
                const uint4 v = *(const uint4*)(w2t + n * 128 + kb * 8);
                *(uint4*)((char*)lw + n * 256 + ((kb * 16) ^ ((n & 7) << 4))) = v;
            }
        }
        __syncthreads();

        floatx4 acc[4];
#pragma unroll
        for (int nt = 0; nt < 4; nt++) acc[nt] = (floatx4){0.f, 0.f, 0.f, 0.f};
        const int swz = (m & 7) << 4;
#pragma unroll
        for (int ks = 0; ks < 4; ks++) {
#pragma unroll
            for (int nt = 0; nt < 4; nt++) {
                const int n = nt * 16 + m;
                const half8 b = *(const half8*)((const char*)lw + n * 256 +
                                                ((ks * 64 + q * 16) ^ swz));
                acc[nt] = __builtin_amdgcn_mfma_f32_16x16x32_f16(av[ks], b, acc[nt], 0, 0, 0);
            }
        }
        __syncthreads();                          // lw reads done; alias as hs
        _Float16* hs = (_Float16*)smem;           // 8KB
        const int lrow0 = wv * 16 + q * 4;
#pragma unroll
        for (int nt = 0; nt < 4; nt++)
#pragma unroll
            for (int r = 0; r < 4; r++)
                hs[(lrow0 + r) * 64 + nt * 16 + m] = (_Float16)acc[nt][r];
        __syncthreads();

#pragma unroll
        for (int i = t; i < 512; i += 256) {
            const int row = i >> 3;
            if (gr0 + row < NN)
                ((half8*)h2h)[(size_t)(gr0 + row) * 8 + (i & 7)] = ((const half8*)hs)[i];
        }
        const int arow = t >> 2, sg = t & 3;
        const int grow = gr0 + arow;
        float ps = 0.f, pd = 0.f;
        const half8*  hp8 = (const half8*)(hs + arow * 64 + sg * 16);
        const float4* s4  = (const float4*)(at_s2 + sg * 16);
        const float4* d4  = (const float4*)(at_d2 + sg * 16);
#pragma unroll
        for (int cc = 0; cc < 2; cc++) {
            const half8 hv = hp8[cc];
            const float4 a = s4[cc * 2], b = s4[cc * 2 + 1];
            const float4 c = d4[cc * 2], e = d4[cc * 2 + 1];
            ps += (float)hv[0]*a.x + (float)hv[1]*a.y + (float)hv[2]*a.z + (float)hv[3]*a.w
                + (float)hv[4]*b.x + (float)hv[5]*b.y + (float)hv[6]*b.z + (float)hv[7]*b.w;
            pd += (float)hv[0]*c.x + (float)hv[1]*c.y + (float)hv[2]*c.z + (float)hv[3]*c.w
                + (float)hv[4]*e.x + (float)hv[5]*e.y + (float)hv[6]*e.z + (float)hv[7]*e.w;
        }
        ps += __shfl_down(ps, 2);  pd += __shfl_down(pd, 2);
        ps += __shfl_down(ps, 1);  pd += __shfl_down(pd, 1);
        if (sg == 0 && grow < NN) { as2[grow] = ps; ad2[grow] = pd; }
        __syncthreads();   // LDS reuse across tiles
    }
    gridbar(slots, genp, 4, nb);

    // ================= P5: agg2 (grid-stride node groups) =================
    {
        float* wbuf = (float*)smem;               // 4 waves x 64 floats
        float* wb = wbuf + wv * 64;
        for (int vb = bid; vb < NGRP; vb += nb) {
            const int d = __builtin_amdgcn_readfirstlane(vb * 4 + wv);
            const int beg = row_beg[d], end = row_end[d];
            const float add = ad2[d];
            float acc = 0.f, den = 0.f;

            for (int jb = beg; jb < end; jb += 64) {
                const int cnt = min(64, end - jb);
                {
                    const int sl = col[jb + min(lane, cnt - 1)];
                    wb[lane] = __expf(lrelu(as2[sl] + add));
                }
                __asm__ volatile("s_waitcnt lgkmcnt(0)" ::: "memory");

                int k = 0;
                for (; k + 16 <= cnt; k += 16) {
                    float w[16], g[16];
#pragma unroll
                    for (int u = 0; u < 16; u++) {
                        const int s = col[jb + k + u];
                        w[u] = wb[k + u];
                        g[u] = (float)h2h[s * 64 + lane];
                    }
#pragma unroll
                    for (int u = 0; u < 16; u++) {
                        den += w[u];
                        acc += w[u] * g[u];
                    }
                }
                for (; k + 4 <= cnt; k += 4) {
                    float w[4], g[4];
#pragma unroll
                    for (int u = 0; u < 4; u++) {
                        const int s = col[jb + k + u];
                        w[u] = wb[k + u];
                        g[u] = (float)h2h[s * 64 + lane];
                    }
#pragma unroll
                    for (int u = 0; u < 4; u++) {
                        den += w[u];
                        acc += w[u] * g[u];
                    }
                }
                for (; k < cnt; k++) {
                    const float w = wb[k];
                    den += w;
                    acc += w * (float)h2h[col[jb + k] * 64 + lane];
                }
                __asm__ volatile("" ::: "memory");
            }
            out[d * 64 + lane] = acc / (den + 1e-16f) + b2[lane];
        }
    }
}

// ---------------------------------------------------------------------------
extern "C" void kernel_launch(void* const* d_in, const int* in_sizes, int n_in,
                              void* d_out, int out_size, void* d_ws, size_t ws_size,
                              hipStream_t stream)
{
    const float* x    = (const float*)d_in[0];
    const int*   ei   = (const int*)  d_in[1];
    const float* W1   = (const float*)d_in[2];
    const float* at_s1= (const float*)d_in[3];
    const float* at_d1= (const float*)d_in[4];
    const float* b1   = (const float*)d_in[5];
    const float* W2   = (const float*)d_in[6];
    const float* at_s2= (const float*)d_in[7];
    const float* at_d2= (const float*)d_in[8];
    const float* b2   = (const float*)d_in[9];
    float*       out  = (float*)d_out;

    const size_t NPAD = (size_t)NBUCK * MAXB;

    // workspace layout (~48 MB); bcnt+gen+slots contiguous for ONE memset
    float* fw   = (float*)d_ws;
    float* as1  = fw;                  // NN*4
    float* ad1  = as1  + NN * 4;       // NN*4
    float* as2  = ad1  + NN * 4;       // NN
    float* ad2  = as2  + NN;           // NN
    _Float16* h1h   = (_Float16*)(ad2 + NN);   // NN*128
    _Float16* act1h = h1h  + (size_t)NN * 128; // NN*128
    _Float16* h2h   = act1h+ (size_t)NN * 128; // NN*64
    _Float16* w1t   = h2h  + (size_t)NN * 64;  // 16384
    _Float16* w2t   = w1t  + 16384;            // 8192
    int*   row_beg = (int*)(w2t + 8192);       // NN
    int*   row_end = row_beg + NN;             // NN
    int*   col     = row_end + NN;             // NPAD
    int*   bcnt    = col + NPAD;               // 4096 ints (stride-16 padded)
    int*   genp    = bcnt + 4096;              // 16 ints (own line)
    int*   slots   = genp + 16;                // GRID ints
    unsigned* pairs = (unsigned*)(slots + GRID); // NPAD

    hipMemsetAsync(bcnt, 0, (4096 + 16 + GRID) * sizeof(int), stream);

    fused_gat_kernel<<<GRID, 256, 0, stream>>>(
        x, ei, W1, W2, at_s1, at_d1, b1, at_s2, at_d2, b2,
        w1t, w2t, bcnt, pairs, row_beg, row_end, col,
        as1, ad1, as2, ad2, h1h, act1h, h2h, out, genp, slots);
}

// Round 9
// 206.451 us; speedup vs baseline: 4.9129x; 1.7849x over previous
//
#include <hip/hip_runtime.h>

#define NN    50000      // nodes
#define NE    800000     // edges (without self loops)
#define NET   850000     // NE + NN (with self loops)
#define NBUCK ((NN + 255) / 256)   // 196 dst-buckets of 256 nodes
#define MAXB  8192       // padded slots per bucket (avg 4352, sigma 66)
#define BINB  256        // bin grid blocks (grid-stride)
#define AGGB  3125       // agg blocks: 16 nodes/block x 3125 = 50000

typedef __fp16 half2_t __attribute__((ext_vector_type(2)));
typedef _Float16 half8 __attribute__((ext_vector_type(8)));
typedef float floatx4 __attribute__((ext_vector_type(4)));

__device__ __forceinline__ float lrelu(float v) { return fmaxf(v, 0.2f * v); }
__device__ __forceinline__ unsigned pk16(float a, float b) {
    half2_t h = __builtin_amdgcn_cvt_pkrtz(a, b);
    return __builtin_bit_cast(unsigned, h);
}
__device__ __forceinline__ float2 unpk16(unsigned u) {
    half2_t h = __builtin_bit_cast(half2_t, u);
    return make_float2((float)h.x, (float)h.y);
}

// ---------------------------------------------------------------------------
// MFMA GEMM1 + alpha1 (R13, verified): W1^T staged in LDS, x loads hoisted.
// ---------------------------------------------------------------------------
__global__ __launch_bounds__(256) void gemm1_mfma_kernel(
    const float* __restrict__ x, const _Float16* __restrict__ w1t,
    const float* __restrict__ att_s, const float* __restrict__ att_d,
    _Float16* __restrict__ h1h, float* __restrict__ as, float* __restrict__ ad)
{
    __shared__ _Float16 lw[128 * 128];  // 32 KB swizzled W1^T
    __shared__ _Float16 hs[64 * 128];   // 16 KB
    const int t    = threadIdx.x;
    const int lane = t & 63;
    const int m    = lane & 15;
    const int q    = lane >> 4;
    const int wv   = t >> 6;
    const int gr0  = blockIdx.x * 64;
    const int rbase = gr0 + wv * 16;

    const int rme = rbase + m;
    const int rc  = rme < NN ? rme : NN - 1;
    const float* ap = x + (size_t)rc * 128 + q * 8;

    float4 f0[4], f1[4];
#pragma unroll
    for (int ks = 0; ks < 4; ks++) {
        f0[ks] = *(const float4*)(ap + ks * 32);
        f1[ks] = *(const float4*)(ap + ks * 32 + 4);
    }

    {
        const int kb = t & 15;
        const int n0 = t >> 4;
#pragma unroll
        for (int it = 0; it < 8; it++) {
            const int n = n0 + it * 16;
            const uint4 v = *(const uint4*)(w1t + n * 128 + kb * 8);
            *(uint4*)((char*)lw + n * 256 + ((kb * 16) ^ ((n & 7) << 4))) = v;
        }
    }
    __syncthreads();

    floatx4 acc[8];
#pragma unroll
    for (int nt = 0; nt < 8; nt++) acc[nt] = (floatx4){0.f, 0.f, 0.f, 0.f};

    const int swz = (m & 7) << 4;
#pragma unroll
    for (int ks = 0; ks < 4; ks++) {
        const uint4 au = make_uint4(pk16(f0[ks].x, f0[ks].y), pk16(f0[ks].z, f0[ks].w),
                                    pk16(f1[ks].x, f1[ks].y), pk16(f1[ks].z, f1[ks].w));
        const half8 a = __builtin_bit_cast(half8, au);
#pragma unroll
        for (int nt = 0; nt < 8; nt++) {
            const int n = nt * 16 + m;
            const half8 b = *(const half8*)((const char*)lw + n * 256 +
                                            ((ks * 64 + q * 16) ^ swz));
            acc[nt] = __builtin_amdgcn_mfma_f32_16x16x32_f16(a, b, acc[nt], 0, 0, 0);
        }
    }

    const int lrow0 = wv * 16 + q * 4;
#pragma unroll
    for (int nt = 0; nt < 8; nt++)
#pragma unroll
        for (int r = 0; r < 4; r++)
            hs[(lrow0 + r) * 128 + nt * 16 + m] = (_Float16)acc[nt][r];
    __syncthreads();

#pragma unroll
    for (int i = t; i < 1024; i += 256) {
        const int row = i >> 4;
        if (gr0 + row < NN)
            ((half8*)h1h)[(size_t)(gr0 + row) * 16 + (i & 15)] = ((const half8*)hs)[i];
    }

    const int arow = t >> 2, hd = t & 3;
    const int grow = gr0 + arow;
    float ps = 0.f, pd = 0.f;
    const half8*  hp8 = (const half8*)(hs + arow * 128 + hd * 32);
    const float4* s4  = (const float4*)(att_s + hd * 32);
    const float4* d4  = (const float4*)(att_d + hd * 32);
#pragma unroll
    for (int cc = 0; cc < 4; cc++) {
        const half8 hv = hp8[cc];
        const float4 a = s4[cc * 2], b = s4[cc * 2 + 1];
        const float4 c = d4[cc * 2], e = d4[cc * 2 + 1];
        ps += (float)hv[0]*a.x + (float)hv[1]*a.y + (float)hv[2]*a.z + (float)hv[3]*a.w
            + (float)hv[4]*b.x + (float)hv[5]*b.y + (float)hv[6]*b.z + (float)hv[7]*b.w;
        pd += (float)hv[0]*c.x + (float)hv[1]*c.y + (float)hv[2]*c.z + (float)hv[3]*c.w
            + (float)hv[4]*e.x + (float)hv[5]*e.y + (float)hv[6]*e.z + (float)hv[7]*e.w;
    }
    if (grow < NN) {
        as[grow * 4 + hd] = ps;
        ad[grow * 4 + hd] = pd;
    }
}

// ---------------------------------------------------------------------------
// MFMA GEMM2 + alpha2 (R13, verified)
// ---------------------------------------------------------------------------
__global__ __launch_bounds__(256) void gemm2_mfma_kernel(
    const _Float16* __restrict__ ah, const _Float16* __restrict__ w2t,
    const float* __restrict__ att_s, const float* __restrict__ att_d,
    _Float16* __restrict__ h2h, float* __restrict__ as, float* __restrict__ ad)
{
    __shared__ _Float16 lw[64 * 128];   // 16 KB swizzled W2^T
    __shared__ _Float16 hs[64 * 64];    // 8 KB
    const int t    = threadIdx.x;
    const int lane = t & 63;
    const int m    = lane & 15;
    const int q    = lane >> 4;
    const int wv   = t >> 6;
    const int gr0  = blockIdx.x * 64;
    const int rbase = gr0 + wv * 16;

    const int rme = rbase + m;
    const int rc  = rme < NN ? rme : NN - 1;
    const _Float16* ap = ah + (size_t)rc * 128 + q * 8;

    half8 av[4];
#pragma unroll
    for (int ks = 0; ks < 4; ks++) av[ks] = *(const half8*)(ap + ks * 32);

    {
        const int kb = t & 15;
        const int n0 = t >> 4;
#pragma unroll
        for (int it = 0; it < 4; it++) {
            const int n = n0 + it * 16;
            const uint4 v = *(const uint4*)(w2t + n * 128 + kb * 8);
            *(uint4*)((char*)lw + n * 256 + ((kb * 16) ^ ((n & 7) << 4))) = v;
        }
    }
    __syncthreads();

    floatx4 acc[4];
#pragma unroll
    for (int nt = 0; nt < 4; nt++) acc[nt] = (floatx4){0.f, 0.f, 0.f, 0.f};

    const int swz = (m & 7) << 4;
#pragma unroll
    for (int ks = 0; ks < 4; ks++) {
#pragma unroll
        for (int nt = 0; nt < 4; nt++) {
            const int n = nt * 16 + m;
            const half8 b = *(const half8*)((const char*)lw + n * 256 +
                                            ((ks * 64 + q * 16) ^ swz));
            acc[nt] = __builtin_amdgcn_mfma_f32_16x16x32_f16(av[ks], b, acc[nt], 0, 0, 0);
        }
    }

    const int lrow0 = wv * 16 + q * 4;
#pragma unroll
    for (int nt = 0; nt < 4; nt++)
#pragma unroll
        for (int r = 0; r < 4; r++)
            hs[(lrow0 + r) * 64 + nt * 16 + m] = (_Float16)acc[nt][r];
    __syncthreads();

#pragma unroll
    for (int i = t; i < 512; i += 256) {
        const int row = i >> 3;
        if (gr0 + row < NN)
            ((half8*)h2h)[(size_t)(gr0 + row) * 8 + (i & 7)] = ((const half8*)hs)[i];
    }

    const int arow = t >> 2, sg = t & 3;
    const int grow = gr0 + arow;
    float ps = 0.f, pd = 0.f;
    const half8*  hp8 = (const half8*)(hs + arow * 64 + sg * 16);
    const float4* s4  = (const float4*)(att_s + sg * 16);
    const float4* d4  = (const float4*)(att_d + sg * 16);
#pragma unroll
    for (int cc = 0; cc < 2; cc++) {
        const half8 hv = hp8[cc];
        const float4 a = s4[cc * 2], b = s4[cc * 2 + 1];
        const float4 c = d4[cc * 2], e = d4[cc * 2 + 1];
        ps += (float)hv[0]*a.x + (float)hv[1]*a.y + (float)hv[2]*a.z + (float)hv[3]*a.w
            + (float)hv[4]*b.x + (float)hv[5]*b.y + (float)hv[6]*b.z + (float)hv[7]*b.w;
        pd += (float)hv[0]*c.x + (float)hv[1]*c.y + (float)hv[2]*c.z + (float)hv[3]*c.w
            + (float)hv[4]*e.x + (float)hv[5]*e.y + (float)hv[6]*e.z + (float)hv[7]*e.w;
    }
    ps += __shfl_down(ps, 2);  pd += __shfl_down(pd, 2);
    ps += __shfl_down(ps, 1);  pd += __shfl_down(pd, 1);
    if (sg == 0 && grow < NN) { as[grow] = ps; ad[grow] = pd; }
}

// ---------------------------------------------------------------------------
// bin (R13, verified): grid-stride, padded bcnt
// ---------------------------------------------------------------------------
__global__ __launch_bounds__(1024) void bin_kernel(const int* __restrict__ ei,
                                                   const float* __restrict__ W1,
                                                   const float* __restrict__ W2,
                                                   _Float16* __restrict__ w1t,
                                                   _Float16* __restrict__ w2t,
                                                   int* __restrict__ bcnt,
                                                   unsigned* __restrict__ pairs)
{
    if (blockIdx.x < 24) {
        const int idx = blockIdx.x * 1024 + threadIdx.x;
        if (idx < 16384) {
            const int k = idx >> 7, n = idx & 127;
            w1t[n * 128 + k] = (_Float16)W1[idx];
        } else {
            const int j = idx - 16384;
            const int k = j >> 6, n = j & 63;
            w2t[n * 128 + k] = (_Float16)W2[j];
        }
    }

    __shared__ int hist[NBUCK], base[NBUCK], cur[NBUCK];
    const int t = threadIdx.x;
    if (t < NBUCK) { hist[t] = 0; cur[t] = 0; }
    __syncthreads();

    for (int e = blockIdx.x * 1024 + t; e < NET; e += BINB * 1024) {
        const int d = (e < NE) ? ei[NE + e] : (e - NE);
        atomicAdd(&hist[d >> 8], 1);
    }
    __syncthreads();
    if (t < NBUCK && hist[t]) base[t] = atomicAdd(&bcnt[t * 16], hist[t]);
    __syncthreads();
    for (int e = blockIdx.x * 1024 + t; e < NET; e += BINB * 1024) {
        int s, d;
        if (e < NE) { s = ei[e]; d = ei[NE + e]; } else { s = d = e - NE; }
        const int bk = d >> 8;
        const int r = atomicAdd(&cur[bk], 1);
        pairs[(size_t)bk * MAXB + base[bk] + r] =
            (unsigned)s | ((unsigned)(d & 255) << 16);
    }
}

// ---------------------------------------------------------------------------
// bsort (R13, verified)
// ---------------------------------------------------------------------------
__global__ __launch_bounds__(1024) void bsort_kernel(
    const int* __restrict__ bcnt, const unsigned* __restrict__ pairs,
    int* __restrict__ row_beg, int* __restrict__ row_end,
    int* __restrict__ col)
{
    __shared__ int hist[256], cur[256], sh[256];
    __shared__ int outl[MAXB];
    const int b = blockIdx.x, t = threadIdx.x;
    const int m = bcnt[b * 16];
    const int gbase = b * MAXB;
    if (t < 256) hist[t] = 0;
    __syncthreads();
    for (int i = t; i < m; i += 1024)
        atomicAdd(&hist[pairs[gbase + i] >> 16], 1);
    __syncthreads();
    if (t < 256) sh[t] = hist[t];
    __syncthreads();
#pragma unroll
    for (int off = 1; off < 256; off <<= 1) {
        int u = (t < 256 && t >= off) ? sh[t - off] : 0;
        __syncthreads();
        if (t < 256) sh[t] += u;
        __syncthreads();
    }
    if (t < 256) {
        const int ex = sh[t] - hist[t];
        cur[t] = ex;
        const int node = (b << 8) + t;
        if (node < NN) {
            row_beg[node] = gbase + ex;
            row_end[node] = gbase + ex + hist[t];
        }
    }
    __syncthreads();
    for (int i = t; i < m; i += 1024) {
        const unsigned p = pairs[gbase + i];
        const int r = atomicAdd(&cur[p >> 16], 1);
        outl[r] = (int)(p & 0xFFFFu);
    }
    __syncthreads();
    for (int i = t; i < m; i += 1024) col[gbase + i] = outl[i];
}

// ---------------------------------------------------------------------------
// Fused layer-1 tail — R17: 1024-thread blocks (16 waves) for stable
// occupancy (R5: 4-wave blocks churned at 61% occ). Inner loop = verified R10.
// ---------------------------------------------------------------------------
__global__ __launch_bounds__(1024) void agg1_fused_kernel(
    const int* __restrict__ row_beg, const int* __restrict__ row_end,
    const int* __restrict__ col, const unsigned* __restrict__ hh,
    const float* __restrict__ as1, const float* __restrict__ ad1,
    const float* __restrict__ b1, unsigned* __restrict__ acth)
{
    __shared__ float wbuf[16][64 * 4];   // [wave][edge*4+head], 16 KB
    const int wv   = threadIdx.x >> 6;
    const int d    = __builtin_amdgcn_readfirstlane(blockIdx.x * 16 + wv);
    const int lane = threadIdx.x & 63;
    const int head = lane >> 4;
    const int beg = row_beg[d], end = row_end[d];
    const float4 ad4 = ((const float4*)ad1)[d];
    float* wb = wbuf[wv];

    float acc0 = 0.f, acc1 = 0.f, den = 0.f;

    for (int jb = beg; jb < end; jb += 64) {
        const int cnt = min(64, end - jb);
        {
            const int sl = col[jb + min(lane, cnt - 1)];
            const float4 a = ((const float4*)as1)[sl];
            float4 w4;
            w4.x = __expf(lrelu(a.x + ad4.x));
            w4.y = __expf(lrelu(a.y + ad4.y));
            w4.z = __expf(lrelu(a.z + ad4.z));
            w4.w = __expf(lrelu(a.w + ad4.w));
            ((float4*)wb)[lane] = w4;
        }
        __asm__ volatile("s_waitcnt lgkmcnt(0)" ::: "memory");

        int k = 0;
        for (; k + 16 <= cnt; k += 16) {
            float    w[16];
            unsigned g[16];
#pragma unroll
            for (int u = 0; u < 16; u++) {
                const int s = col[jb + k + u];        // s_load (uniform)
                w[u] = wb[(k + u) * 4 + head];        // ds_read broadcast
                g[u] = hh[s * 64 + lane];             // saddr + voffset
            }
#pragma unroll
            for (int u = 0; u < 16; u++) {
                const float2 g2 = unpk16(g[u]);
                den  += w[u];
                acc0 += w[u] * g2.x;
                acc1 += w[u] * g2.y;
            }
        }
        for (; k + 4 <= cnt; k += 4) {
            float    w[4];
            unsigned g[4];
#pragma unroll
            for (int u = 0; u < 4; u++) {
                const int s = col[jb + k + u];
                w[u] = wb[(k + u) * 4 + head];
                g[u] = hh[s * 64 + lane];
            }
#pragma unroll
            for (int u = 0; u < 4; u++) {
                const float2 g2 = unpk16(g[u]);
                den  += w[u];
                acc0 += w[u] * g2.x;
                acc1 += w[u] * g2.y;
            }
        }
        for (; k < cnt; k++) {
            const float w = wb[k * 4 + head];
            const float2 g2 = unpk16(hh[col[jb + k] * 64 + lane]);
            den  += w;
            acc0 += w * g2.x;
            acc1 += w * g2.y;
        }
        __asm__ volatile("" ::: "memory");
    }
    const float2 bb  = ((const float2*)b1)[lane];
    const float  inv = 1.f / (den + 1e-16f);
    float v0 = acc0 * inv + bb.x;
    float v1 = acc1 * inv + bb.y;
    v0 = v0 > 0.f ? v0 : (__expf(v0) - 1.f);
    v1 = v1 > 0.f ? v1 : (__expf(v1) - 1.f);
    acth[d * 64 + lane] = pk16(v0, v1);
}

// ---------------------------------------------------------------------------
// Fused layer-2 tail — R17: 1024-thread blocks + 2 edges/wave.
// half = lane>>5 (edge slot), c = lane&31 (channels 2c,2c+1 via u32 load).
// VMEM gather instructions halve; transactions full-width (4B/lane).
// ---------------------------------------------------------------------------
__global__ __launch_bounds__(1024) void agg2_fused_kernel(
    const int* __restrict__ row_beg, const int* __restrict__ row_end,
    const int* __restrict__ col, const _Float16* __restrict__ h,
    const float* __restrict__ as2, const float* __restrict__ ad2,
    const float* __restrict__ b2, float* __restrict__ out)
{
    __shared__ float wbuf[16][64];   // 4 KB
    const int wv   = threadIdx.x >> 6;
    const int d    = __builtin_amdgcn_readfirstlane(blockIdx.x * 16 + wv);
    const int lane = threadIdx.x & 63;
    const int half = lane >> 5;      // edge slot 0/1
    const int c    = lane & 31;      // channel pair 2c,2c+1
    const int beg = row_beg[d], end = row_end[d];
    const float add = ad2[d];
    float* wb = wbuf[wv];
    const unsigned* __restrict__ h2 = (const unsigned*)h;

    float acc0 = 0.f, acc1 = 0.f, den = 0.f;

    for (int jb = beg; jb < end; jb += 64) {
        const int cnt = min(64, end - jb);
        {
            const int sl = col[jb + min(lane, cnt - 1)];
            wb[lane] = __expf(lrelu(as2[sl] + add));
        }
        __asm__ volatile("s_waitcnt lgkmcnt(0)" ::: "memory");

        int k = 0;
        for (; k + 16 <= cnt; k += 16) {
            float    w[8];
            unsigned g[8];
#pragma unroll
            for (int u = 0; u < 8; u++) {
                const int e = jb + k + 2 * u + half;
                const int s = col[e];                 // 2 addrs per wave
                w[u] = wb[k + 2 * u + half];          // 2-way ds broadcast (free)
                g[u] = h2[(size_t)s * 32 + c];        // u32 = 2 channels
            }
#pragma unroll
            for (int u = 0; u < 8; u++) {
                const float2 g2 = unpk16(g[u]);
                den  += w[u];
                acc0 += w[u] * g2.x;
                acc1 += w[u] * g2.y;
            }
        }
        for (; k < cnt; k += 2) {
            const int  e   = k + half;
            const bool ok  = e < cnt;
            const int  s   = col[jb + (ok ? e : cnt - 1)];
            const float w  = ok ? wb[e] : 0.f;
            const float2 g2 = unpk16(h2[(size_t)s * 32 + c]);
            den  += w;
            acc0 += w * g2.x;
            acc1 += w * g2.y;
        }
        __asm__ volatile("" ::: "memory");
    }
    // combine the 2 edge slots (lanes c and c+32 hold the same channels)
    acc0 += __shfl_xor(acc0, 32);
    acc1 += __shfl_xor(acc1, 32);
    den  += __shfl_xor(den, 32);

    if (half == 0) {
        const float inv = 1.f / (den + 1e-16f);
        const float2 bb = ((const float2*)b2)[c];
        float2 o;
        o.x = acc0 * inv + bb.x;
        o.y = acc1 * inv + bb.y;
        ((float2*)out)[(size_t)d * 32 + c] = o;
    }
}

// ---------------------------------------------------------------------------
extern "C" void kernel_launch(void* const* d_in, const int* in_sizes, int n_in,
                              void* d_out, int out_size, void* d_ws, size_t ws_size,
                              hipStream_t stream)
{
    const float* x    = (const float*)d_in[0];
    const int*   ei   = (const int*)  d_in[1];
    const float* W1   = (const float*)d_in[2];
    const float* at_s1= (const float*)d_in[3];
    const float* at_d1= (const float*)d_in[4];
    const float* b1   = (const float*)d_in[5];
    const float* W2   = (const float*)d_in[6];
    const float* at_s2= (const float*)d_in[7];
    const float* at_d2= (const float*)d_in[8];
    const float* b2   = (const float*)d_in[9];
    float*       out  = (float*)d_out;

    const size_t NPAD = (size_t)NBUCK * MAXB;

    // workspace layout (~48 MB)
    float* fw   = (float*)d_ws;
    float* as1  = fw;                  // NN*4
    float* ad1  = as1  + NN * 4;       // NN*4
    float* as2  = ad1  + NN * 4;       // NN
    float* ad2  = as2  + NN;           // NN
    _Float16* h1h   = (_Float16*)(ad2 + NN);   // NN*128
    _Float16* act1h = h1h  + (size_t)NN * 128; // NN*128
    _Float16* h2h   = act1h+ (size_t)NN * 128; // NN*64
    _Float16* w1t   = h2h  + (size_t)NN * 64;  // 16384
    _Float16* w2t   = w1t  + 16384;            // 8192
    int*   row_beg = (int*)(w2t + 8192);       // NN
    int*   row_end = row_beg + NN;             // NN
    int*   col     = row_end + NN;             // NPAD
    int*   bcnt    = col + NPAD;               // 4096 ints (stride-16 padded)
    unsigned* pairs = (unsigned*)(bcnt + 4096); // NPAD

    hipMemsetAsync(bcnt, 0, 4096 * sizeof(int), stream);

    const int gemm_grid = (NN + 63) / 64;   // 782

    bin_kernel  <<<BINB, 1024, 0, stream>>>(ei, W1, W2, w1t, w2t, bcnt, pairs);
    bsort_kernel<<<NBUCK, 1024, 0, stream>>>(bcnt, pairs, row_beg, row_end, col);

    // layer 1
    gemm1_mfma_kernel<<<gemm_grid, 256, 0, stream>>>(x, w1t, at_s1, at_d1, h1h, as1, ad1);
    agg1_fused_kernel<<<AGGB, 1024, 0, stream>>>(row_beg, row_end, col,
                        (const unsigned*)h1h, as1, ad1, b1, (unsigned*)act1h);

    // layer 2
    gemm2_mfma_kernel<<<gemm_grid, 256, 0, stream>>>(act1h, w2t, at_s2, at_d2, h2h, as2, ad2);
    agg2_fused_kernel<<<AGGB, 1024, 0, stream>>>(row_beg, row_end, col,
                        h2h, as2, ad2, b2, out);
}

// Round 10
// 195.744 us; speedup vs baseline: 5.1817x; 1.0547x over previous
//
#include <hip/hip_runtime.h>

#define NN    50000      // nodes
#define NE    800000     // edges (without self loops)
#define NET   850000     // NE + NN (with self loops)
#define NBUCK ((NN + 255) / 256)   // 196 dst-buckets of 256 nodes
#define MAXB  8192       // padded slots per bucket (avg 4352, sigma 66)
#define BINB  256        // bin grid blocks (grid-stride)
#define GTILE 782        // (NN+63)/64 gemm row-tiles

typedef __fp16 half2_t __attribute__((ext_vector_type(2)));
typedef _Float16 half8 __attribute__((ext_vector_type(8)));
typedef float floatx4 __attribute__((ext_vector_type(4)));

__device__ __forceinline__ float lrelu(float v) { return fmaxf(v, 0.2f * v); }
__device__ __forceinline__ unsigned pk16(float a, float b) {
    half2_t h = __builtin_amdgcn_cvt_pkrtz(a, b);
    return __builtin_bit_cast(unsigned, h);
}
__device__ __forceinline__ float2 unpk16(unsigned u) {
    half2_t h = __builtin_bit_cast(half2_t, u);
    return make_float2((float)h.x, (float)h.y);
}

// ---------------------------------------------------------------------------
// bin (R13, verified): grid-stride, padded bcnt, folded weight prep
// ---------------------------------------------------------------------------
__global__ __launch_bounds__(1024) void bin_kernel(const int* __restrict__ ei,
                                                   const float* __restrict__ W1,
                                                   const float* __restrict__ W2,
                                                   _Float16* __restrict__ w1t,
                                                   _Float16* __restrict__ w2t,
                                                   int* __restrict__ bcnt,
                                                   unsigned* __restrict__ pairs)
{
    if (blockIdx.x < 24) {
        const int idx = blockIdx.x * 1024 + threadIdx.x;
        if (idx < 16384) {
            const int k = idx >> 7, n = idx & 127;
            w1t[n * 128 + k] = (_Float16)W1[idx];
        } else {
            const int j = idx - 16384;
            const int k = j >> 6, n = j & 63;
            w2t[n * 128 + k] = (_Float16)W2[j];
        }
    }

    __shared__ int hist[NBUCK], base[NBUCK], cur[NBUCK];
    const int t = threadIdx.x;
    if (t < NBUCK) { hist[t] = 0; cur[t] = 0; }
    __syncthreads();

    for (int e = blockIdx.x * 1024 + t; e < NET; e += BINB * 1024) {
        const int d = (e < NE) ? ei[NE + e] : (e - NE);
        atomicAdd(&hist[d >> 8], 1);
    }
    __syncthreads();
    if (t < NBUCK && hist[t]) base[t] = atomicAdd(&bcnt[t * 16], hist[t]);
    __syncthreads();
    for (int e = blockIdx.x * 1024 + t; e < NET; e += BINB * 1024) {
        int s, d;
        if (e < NE) { s = ei[e]; d = ei[NE + e]; } else { s = d = e - NE; }
        const int bk = d >> 8;
        const int r = atomicAdd(&cur[bk], 1);
        pairs[(size_t)bk * MAXB + base[bk] + r] =
            (unsigned)s | ((unsigned)(d & 255) << 16);
    }
}

// ---------------------------------------------------------------------------
// MERGED bsort || gemm1 — R18: both depend only on bin, so one launch.
// Blocks 0..195: bsort bucket (256-thread variant, verified R6-R8).
// Blocks 196..977: gemm1 tile (R13 internals, verified).
// ---------------------------------------------------------------------------
__global__ __launch_bounds__(256) void bsortgemm1_kernel(
    const int* __restrict__ bcnt, const unsigned* __restrict__ pairs,
    int* __restrict__ row_beg, int* __restrict__ row_end, int* __restrict__ col,
    const float* __restrict__ x, const _Float16* __restrict__ w1t,
    const float* __restrict__ att_s, const float* __restrict__ att_d,
    _Float16* __restrict__ h1h, float* __restrict__ as, float* __restrict__ ad)
{
    __shared__ __align__(16) char smem[49152];   // gemm: lw 32K + hs 16K; bsort: 35K
    const int t = threadIdx.x;

    if (blockIdx.x < NBUCK) {
        // ---------------- bsort bucket (256 threads) ----------------
        const int b = blockIdx.x;
        int* hist = (int*)smem;
        int* cur  = hist + 256;
        int* sh   = cur + 256;
        int* outl = sh + 256;                    // MAXB ints = 32KB
        const int m = bcnt[b * 16];
        const int gbase = b * MAXB;
        hist[t] = 0;
        __syncthreads();
        for (int i = t; i < m; i += 256)
            atomicAdd(&hist[pairs[gbase + i] >> 16], 1);
        __syncthreads();
        sh[t] = hist[t];
        __syncthreads();
#pragma unroll
        for (int off = 1; off < 256; off <<= 1) {
            const int u = (t >= off) ? sh[t - off] : 0;
            __syncthreads();
            sh[t] += u;
            __syncthreads();
        }
        {
            const int ex = sh[t] - hist[t];
            cur[t] = ex;
            const int node = (b << 8) + t;
            if (node < NN) {
                row_beg[node] = gbase + ex;
                row_end[node] = gbase + ex + hist[t];
            }
        }
        __syncthreads();
        for (int i = t; i < m; i += 256) {
            const unsigned p = pairs[gbase + i];
            const int r = atomicAdd(&cur[p >> 16], 1);
            outl[r] = (int)(p & 0xFFFFu);
        }
        __syncthreads();
        for (int i = t; i < m; i += 256) col[gbase + i] = outl[i];
    } else {
        // ---------------- gemm1 tile (R13 internals) ----------------
        const int tile = blockIdx.x - NBUCK;
        _Float16* lw = (_Float16*)smem;          // 32KB swizzled W1^T
        _Float16* hs = (_Float16*)(smem + 32768); // 16KB
        const int lane = t & 63;
        const int m    = lane & 15;
        const int q    = lane >> 4;
        const int wv   = t >> 6;
        const int gr0  = tile * 64;
        const int rme  = gr0 + wv * 16 + m;
        const int rc   = rme < NN ? rme : NN - 1;
        const float* ap = x + (size_t)rc * 128 + q * 8;

        float4 f0[4], f1[4];
#pragma unroll
        for (int ks = 0; ks < 4; ks++) {
            f0[ks] = *(const float4*)(ap + ks * 32);
            f1[ks] = *(const float4*)(ap + ks * 32 + 4);
        }
        {
            const int kb = t & 15;
            const int n0 = t >> 4;
#pragma unroll
            for (int it = 0; it < 8; it++) {
                const int n = n0 + it * 16;
                const uint4 v = *(const uint4*)(w1t + n * 128 + kb * 8);
                *(uint4*)((char*)lw + n * 256 + ((kb * 16) ^ ((n & 7) << 4))) = v;
            }
        }
        __syncthreads();

        floatx4 acc[8];
#pragma unroll
        for (int nt = 0; nt < 8; nt++) acc[nt] = (floatx4){0.f, 0.f, 0.f, 0.f};

        const int swz = (m & 7) << 4;
#pragma unroll
        for (int ks = 0; ks < 4; ks++) {
            const uint4 au = make_uint4(pk16(f0[ks].x, f0[ks].y), pk16(f0[ks].z, f0[ks].w),
                                        pk16(f1[ks].x, f1[ks].y), pk16(f1[ks].z, f1[ks].w));
            const half8 a = __builtin_bit_cast(half8, au);
#pragma unroll
            for (int nt = 0; nt < 8; nt++) {
                const int n = nt * 16 + m;
                const half8 b = *(const half8*)((const char*)lw + n * 256 +
                                                ((ks * 64 + q * 16) ^ swz));
                acc[nt] = __builtin_amdgcn_mfma_f32_16x16x32_f16(a, b, acc[nt], 0, 0, 0);
            }
        }

        const int lrow0 = wv * 16 + q * 4;
#pragma unroll
        for (int nt = 0; nt < 8; nt++)
#pragma unroll
            for (int r = 0; r < 4; r++)
                hs[(lrow0 + r) * 128 + nt * 16 + m] = (_Float16)acc[nt][r];
        __syncthreads();

#pragma unroll
        for (int i = t; i < 1024; i += 256) {
            const int row = i >> 4;
            if (gr0 + row < NN)
                ((half8*)h1h)[(size_t)(gr0 + row) * 16 + (i & 15)] = ((const half8*)hs)[i];
        }

        const int arow = t >> 2, hd = t & 3;
        const int grow = gr0 + arow;
        float ps = 0.f, pd = 0.f;
        const half8*  hp8 = (const half8*)(hs + arow * 128 + hd * 32);
        const float4* s4  = (const float4*)(att_s + hd * 32);
        const float4* d4  = (const float4*)(att_d + hd * 32);
#pragma unroll
        for (int cc = 0; cc < 4; cc++) {
            const half8 hv = hp8[cc];
            const float4 a = s4[cc * 2], b = s4[cc * 2 + 1];
            const float4 c = d4[cc * 2], e = d4[cc * 2 + 1];
            ps += (float)hv[0]*a.x + (float)hv[1]*a.y + (float)hv[2]*a.z + (float)hv[3]*a.w
                + (float)hv[4]*b.x + (float)hv[5]*b.y + (float)hv[6]*b.z + (float)hv[7]*b.w;
            pd += (float)hv[0]*c.x + (float)hv[1]*c.y + (float)hv[2]*c.z + (float)hv[3]*c.w
                + (float)hv[4]*e.x + (float)hv[5]*e.y + (float)hv[6]*e.z + (float)hv[7]*e.w;
        }
        if (grow < NN) {
            as[grow * 4 + hd] = ps;
            ad[grow * 4 + hd] = pd;
        }
    }
}

// ---------------------------------------------------------------------------
// MFMA GEMM2 + alpha2 (R13, verified)
// ---------------------------------------------------------------------------
__global__ __launch_bounds__(256) void gemm2_mfma_kernel(
    const _Float16* __restrict__ ah, const _Float16* __restrict__ w2t,
    const float* __restrict__ att_s, const float* __restrict__ att_d,
    _Float16* __restrict__ h2h, float* __restrict__ as, float* __restrict__ ad)
{
    __shared__ _Float16 lw[64 * 128];   // 16 KB swizzled W2^T
    __shared__ _Float16 hs[64 * 64];    // 8 KB
    const int t    = threadIdx.x;
    const int lane = t & 63;
    const int m    = lane & 15;
    const int q    = lane >> 4;
    const int wv   = t >> 6;
    const int gr0  = blockIdx.x * 64;
    const int rbase = gr0 + wv * 16;

    const int rme = rbase + m;
    const int rc  = rme < NN ? rme : NN - 1;
    const _Float16* ap = ah + (size_t)rc * 128 + q * 8;

    half8 av[4];
#pragma unroll
    for (int ks = 0; ks < 4; ks++) av[ks] = *(const half8*)(ap + ks * 32);

    {
        const int kb = t & 15;
        const int n0 = t >> 4;
#pragma unroll
        for (int it = 0; it < 4; it++) {
            const int n = n0 + it * 16;
            const uint4 v = *(const uint4*)(w2t + n * 128 + kb * 8);
            *(uint4*)((char*)lw + n * 256 + ((kb * 16) ^ ((n & 7) << 4))) = v;
        }
    }
    __syncthreads();

    floatx4 acc[4];
#pragma unroll
    for (int nt = 0; nt < 4; nt++) acc[nt] = (floatx4){0.f, 0.f, 0.f, 0.f};

    const int swz = (m & 7) << 4;
#pragma unroll
    for (int ks = 0; ks < 4; ks++) {
#pragma unroll
        for (int nt = 0; nt < 4; nt++) {
            const int n = nt * 16 + m;
            const half8 b = *(const half8*)((const char*)lw + n * 256 +
                                            ((ks * 64 + q * 16) ^ swz));
            acc[nt] = __builtin_amdgcn_mfma_f32_16x16x32_f16(av[ks], b, acc[nt], 0, 0, 0);
        }
    }

    const int lrow0 = wv * 16 + q * 4;
#pragma unroll
    for (int nt = 0; nt < 4; nt++)
#pragma unroll
        for (int r = 0; r < 4; r++)
            hs[(lrow0 + r) * 64 + nt * 16 + m] = (_Float16)acc[nt][r];
    __syncthreads();

#pragma unroll
    for (int i = t; i < 512; i += 256) {
        const int row = i >> 3;
        if (gr0 + row < NN)
            ((half8*)h2h)[(size_t)(gr0 + row) * 8 + (i & 7)] = ((const half8*)hs)[i];
    }

    const int arow = t >> 2, sg = t & 3;
    const int grow = gr0 + arow;
    float ps = 0.f, pd = 0.f;
    const half8*  hp8 = (const half8*)(hs + arow * 64 + sg * 16);
    const float4* s4  = (const float4*)(att_s + sg * 16);
    const float4* d4  = (const float4*)(att_d + sg * 16);
#pragma unroll
    for (int cc = 0; cc < 2; cc++) {
        const half8 hv = hp8[cc];
        const float4 a = s4[cc * 2], b = s4[cc * 2 + 1];
        const float4 c = d4[cc * 2], e = d4[cc * 2 + 1];
        ps += (float)hv[0]*a.x + (float)hv[1]*a.y + (float)hv[2]*a.z + (float)hv[3]*a.w
            + (float)hv[4]*b.x + (float)hv[5]*b.y + (float)hv[6]*b.z + (float)hv[7]*b.w;
        pd += (float)hv[0]*c.x + (float)hv[1]*c.y + (float)hv[2]*c.z + (float)hv[3]*c.w
            + (float)hv[4]*e.x + (float)hv[5]*e.y + (float)hv[6]*e.z + (float)hv[7]*e.w;
    }
    ps += __shfl_down(ps, 2);  pd += __shfl_down(pd, 2);
    ps += __shfl_down(ps, 1);  pd += __shfl_down(pd, 1);
    if (sg == 0 && grow < NN) { as[grow] = ps; ad[grow] = pd; }
}

// ---------------------------------------------------------------------------
// Fused layer-1 tail (R10/R4 structure, verified at 256 threads)
// ---------------------------------------------------------------------------
__global__ __launch_bounds__(256) void agg1_fused_kernel(
    const int* __restrict__ row_beg, const int* __restrict__ row_end,
    const int* __restrict__ col, const unsigned* __restrict__ hh,
    const float* __restrict__ as1, const float* __restrict__ ad1,
    const float* __restrict__ b1, unsigned* __restrict__ acth)
{
    __shared__ float wbuf[4][64 * 4];   // [wave][edge*4+head], 4 KB
    const int wv   = threadIdx.x >> 6;
    const int d    = __builtin_amdgcn_readfirstlane((blockIdx.x * 256 + threadIdx.x) >> 6);
    const int lane = threadIdx.x & 63;
    const int head = lane >> 4;
    const int beg = row_beg[d], end = row_end[d];
    const float4 ad4 = ((const float4*)ad1)[d];
    float* wb = wbuf[wv];

    float acc0 = 0.f, acc1 = 0.f, den = 0.f;

    for (int jb = beg; jb < end; jb += 64) {
        const int cnt = min(64, end - jb);
        {
            const int sl = col[jb + min(lane, cnt - 1)];
            const float4 a = ((const float4*)as1)[sl];
            float4 w4;
            w4.x = __expf(lrelu(a.x + ad4.x));
            w4.y = __expf(lrelu(a.y + ad4.y));
            w4.z = __expf(lrelu(a.z + ad4.z));
            w4.w = __expf(lrelu(a.w + ad4.w));
            ((float4*)wb)[lane] = w4;
        }
        __asm__ volatile("s_waitcnt lgkmcnt(0)" ::: "memory");

        int k = 0;
        for (; k + 16 <= cnt; k += 16) {
            float    w[16];
            unsigned g[16];
#pragma unroll
            for (int u = 0; u < 16; u++) {
                const int s = col[jb + k + u];        // s_load (uniform)
                w[u] = wb[(k + u) * 4 + head];        // ds_read broadcast
                g[u] = hh[s * 64 + lane];             // saddr + voffset
            }
#pragma unroll
            for (int u = 0; u < 16; u++) {
                const float2 g2 = unpk16(g[u]);
                den  += w[u];
                acc0 += w[u] * g2.x;
                acc1 += w[u] * g2.y;
            }
        }
        for (; k + 4 <= cnt; k += 4) {
            float    w[4];
            unsigned g[4];
#pragma unroll
            for (int u = 0; u < 4; u++) {
                const int s = col[jb + k + u];
                w[u] = wb[(k + u) * 4 + head];
                g[u] = hh[s * 64 + lane];
            }
#pragma unroll
            for (int u = 0; u < 4; u++) {
                const float2 g2 = unpk16(g[u]);
                den  += w[u];
                acc0 += w[u] * g2.x;
                acc1 += w[u] * g2.y;
            }
        }
        for (; k < cnt; k++) {
            const float w = wb[k * 4 + head];
            const float2 g2 = unpk16(hh[col[jb + k] * 64 + lane]);
            den  += w;
            acc0 += w * g2.x;
            acc1 += w * g2.y;
        }
        __asm__ volatile("" ::: "memory");
    }
    const float2 bb  = ((const float2*)b1)[lane];
    const float  inv = 1.f / (den + 1e-16f);
    float v0 = acc0 * inv + bb.x;
    float v1 = acc1 * inv + bb.y;
    v0 = v0 > 0.f ? v0 : (__expf(v0) - 1.f);
    v1 = v1 > 0.f ? v1 : (__expf(v1) - 1.f);
    acth[d * 64 + lane] = pk16(v0, v1);
}

// ---------------------------------------------------------------------------
// Fused layer-2 tail — R18: 256-thread blocks (R4 granularity) with the
// 2-edge/wave u32 gather (R17 inner, verified numerics in R9).
// ---------------------------------------------------------------------------
__global__ __launch_bounds__(256) void agg2_fused_kernel(
    const int* __restrict__ row_beg, const int* __restrict__ row_end,
    const int* __restrict__ col, const _Float16* __restrict__ h,
    const float* __restrict__ as2, const float* __restrict__ ad2,
    const float* __restrict__ b2, float* __restrict__ out)
{
    __shared__ float wbuf[4][64];   // 1 KB
    const int wv   = threadIdx.x >> 6;
    const int d    = __builtin_amdgcn_readfirstlane(blockIdx.x * 4 + wv);
    const int lane = threadIdx.x & 63;
    const int half = lane >> 5;      // edge slot 0/1
    const int c    = lane & 31;      // channel pair 2c,2c+1
    const int beg = row_beg[d], end = row_end[d];
    const float add = ad2[d];
    float* wb = wbuf[wv];
    const unsigned* __restrict__ h2 = (const unsigned*)h;

    float acc0 = 0.f, acc1 = 0.f, den = 0.f;

    for (int jb = beg; jb < end; jb += 64) {
        const int cnt = min(64, end - jb);
        {
            const int sl = col[jb + min(lane, cnt - 1)];
            wb[lane] = __expf(lrelu(as2[sl] + add));
        }
        __asm__ volatile("s_waitcnt lgkmcnt(0)" ::: "memory");

        int k = 0;
        for (; k + 16 <= cnt; k += 16) {
            float    w[8];
            unsigned g[8];
#pragma unroll
            for (int u = 0; u < 8; u++) {
                const int e = jb + k + 2 * u + half;
                const int s = col[e];
                w[u] = wb[k + 2 * u + half];
                g[u] = h2[(size_t)s * 32 + c];
            }
#pragma unroll
            for (int u = 0; u < 8; u++) {
                const float2 g2 = unpk16(g[u]);
                den  += w[u];
                acc0 += w[u] * g2.x;
                acc1 += w[u] * g2.y;
            }
        }
        for (; k < cnt; k += 2) {
            const int  e   = k + half;
            const bool ok  = e < cnt;
            const int  s   = col[jb + (ok ? e : cnt - 1)];
            const float w  = ok ? wb[e] : 0.f;
            const float2 g2 = unpk16(h2[(size_t)s * 32 + c]);
            den  += w;
            acc0 += w * g2.x;
            acc1 += w * g2.y;
        }
        __asm__ volatile("" ::: "memory");
    }
    acc0 += __shfl_xor(acc0, 32);
    acc1 += __shfl_xor(acc1, 32);
    den  += __shfl_xor(den, 32);

    if (half == 0) {
        const float inv = 1.f / (den + 1e-16f);
        const float2 bb = ((const float2*)b2)[c];
        float2 o;
        o.x = acc0 * inv + bb.x;
        o.y = acc1 * inv + bb.y;
        ((float2*)out)[(size_t)d * 32 + c] = o;
    }
}

// ---------------------------------------------------------------------------
extern "C" void kernel_launch(void* const* d_in, const int* in_sizes, int n_in,
                              void* d_out, int out_size, void* d_ws, size_t ws_size,
                              hipStream_t stream)
{
    const float* x    = (const float*)d_in[0];
    const int*   ei   = (const int*)  d_in[1];
    const float* W1   = (const float*)d_in[2];
    const float* at_s1= (const float*)d_in[3];
    const float* at_d1= (const float*)d_in[4];
    const float* b1   = (const float*)d_in[5];
    const float* W2   = (const float*)d_in[6];
    const float* at_s2= (const float*)d_in[7];
    const float* at_d2= (const float*)d_in[8];
    const float* b2   = (const float*)d_in[9];
    float*       out  = (float*)d_out;

    const size_t NPAD = (size_t)NBUCK * MAXB;

    // workspace layout (~48 MB)
    float* fw   = (float*)d_ws;
    float* as1  = fw;                  // NN*4
    float* ad1  = as1  + NN * 4;       // NN*4
    float* as2  = ad1  + NN * 4;       // NN
    float* ad2  = as2  + NN;           // NN
    _Float16* h1h   = (_Float16*)(ad2 + NN);   // NN*128
    _Float16* act1h = h1h  + (size_t)NN * 128; // NN*128
    _Float16* h2h   = act1h+ (size_t)NN * 128; // NN*64
    _Float16* w1t   = h2h  + (size_t)NN * 64;  // 16384
    _Float16* w2t   = w1t  + 16384;            // 8192
    int*   row_beg = (int*)(w2t + 8192);       // NN
    int*   row_end = row_beg + NN;             // NN
    int*   col     = row_end + NN;             // NPAD
    int*   bcnt    = col + NPAD;               // 4096 ints (stride-16 padded)
    unsigned* pairs = (unsigned*)(bcnt + 4096); // NPAD

    hipMemsetAsync(bcnt, 0, 4096 * sizeof(int), stream);

    const int node_wave_grid = NN / 4;      // 12500 blocks (wave per node)

    bin_kernel<<<BINB, 1024, 0, stream>>>(ei, W1, W2, w1t, w2t, bcnt, pairs);

    // merged: bsort (blocks 0..195) || gemm1 (blocks 196..977)
    bsortgemm1_kernel<<<NBUCK + GTILE, 256, 0, stream>>>(
        bcnt, pairs, row_beg, row_end, col,
        x, w1t, at_s1, at_d1, h1h, as1, ad1);

    agg1_fused_kernel<<<node_wave_grid, 256, 0, stream>>>(row_beg, row_end, col,
                        (const unsigned*)h1h, as1, ad1, b1, (unsigned*)act1h);

    gemm2_mfma_kernel<<<(NN + 63) / 64, 256, 0, stream>>>(act1h, w2t, at_s2, at_d2, h2h, as2, ad2);
    agg2_fused_kernel<<<node_wave_grid, 256, 0, stream>>>(row_beg, row_end, col,
                        h2h, as2, ad2, b2, out);
}

// Round 11
// 189.292 us; speedup vs baseline: 5.3583x; 1.0341x over previous
//
#include <hip/hip_runtime.h>

#define NN    50000      // nodes
#define NE    800000     // edges (without self loops)
#define NET   850000     // NE + NN (with self loops)
#define NBUCK ((NN + 255) / 256)   // 196 dst-buckets of 256 nodes
#define MAXB  8192       // padded slots per bucket (avg 4352, sigma 66)
#define BINB  256        // bin grid blocks (grid-stride)

typedef __fp16 half2_t __attribute__((ext_vector_type(2)));
typedef _Float16 half8 __attribute__((ext_vector_type(8)));
typedef float floatx4 __attribute__((ext_vector_type(4)));

__device__ __forceinline__ float lrelu(float v) { return fmaxf(v, 0.2f * v); }
__device__ __forceinline__ unsigned pk16(float a, float b) {
    half2_t h = __builtin_amdgcn_cvt_pkrtz(a, b);
    return __builtin_bit_cast(unsigned, h);
}
__device__ __forceinline__ float2 unpk16(unsigned u) {
    half2_t h = __builtin_bit_cast(half2_t, u);
    return make_float2((float)h.x, (float)h.y);
}

// ---------------------------------------------------------------------------
// MFMA GEMM1 + alpha1 (R13, verified 186.6): W1^T staged in LDS, x hoisted.
// ---------------------------------------------------------------------------
__global__ __launch_bounds__(256) void gemm1_mfma_kernel(
    const float* __restrict__ x, const _Float16* __restrict__ w1t,
    const float* __restrict__ att_s, const float* __restrict__ att_d,
    _Float16* __restrict__ h1h, float* __restrict__ as, float* __restrict__ ad)
{
    __shared__ _Float16 lw[128 * 128];  // 32 KB swizzled W1^T
    __shared__ _Float16 hs[64 * 128];   // 16 KB
    const int t    = threadIdx.x;
    const int lane = t & 63;
    const int m    = lane & 15;
    const int q    = lane >> 4;
    const int wv   = t >> 6;
    const int gr0  = blockIdx.x * 64;
    const int rbase = gr0 + wv * 16;

    const int rme = rbase + m;
    const int rc  = rme < NN ? rme : NN - 1;
    const float* ap = x + (size_t)rc * 128 + q * 8;

    float4 f0[4], f1[4];
#pragma unroll
    for (int ks = 0; ks < 4; ks++) {
        f0[ks] = *(const float4*)(ap + ks * 32);
        f1[ks] = *(const float4*)(ap + ks * 32 + 4);
    }

    {
        const int kb = t & 15;
        const int n0 = t >> 4;
#pragma unroll
        for (int it = 0; it < 8; it++) {
            const int n = n0 + it * 16;
            const uint4 v = *(const uint4*)(w1t + n * 128 + kb * 8);
            *(uint4*)((char*)lw + n * 256 + ((kb * 16) ^ ((n & 7) << 4))) = v;
        }
    }
    __syncthreads();

    floatx4 acc[8];
#pragma unroll
    for (int nt = 0; nt < 8; nt++) acc[nt] = (floatx4){0.f, 0.f, 0.f, 0.f};

    const int swz = (m & 7) << 4;
#pragma unroll
    for (int ks = 0; ks < 4; ks++) {
        const uint4 au = make_uint4(pk16(f0[ks].x, f0[ks].y), pk16(f0[ks].z, f0[ks].w),
                                    pk16(f1[ks].x, f1[ks].y), pk16(f1[ks].z, f1[ks].w));
        const half8 a = __builtin_bit_cast(half8, au);
#pragma unroll
        for (int nt = 0; nt < 8; nt++) {
            const int n = nt * 16 + m;
            const half8 b = *(const half8*)((const char*)lw + n * 256 +
                                            ((ks * 64 + q * 16) ^ swz));
            acc[nt] = __builtin_amdgcn_mfma_f32_16x16x32_f16(a, b, acc[nt], 0, 0, 0);
        }
    }

    const int lrow0 = wv * 16 + q * 4;
#pragma unroll
    for (int nt = 0; nt < 8; nt++)
#pragma unroll
        for (int r = 0; r < 4; r++)
            hs[(lrow0 + r) * 128 + nt * 16 + m] = (_Float16)acc[nt][r];
    __syncthreads();

#pragma unroll
    for (int i = t; i < 1024; i += 256) {
        const int row = i >> 4;
        if (gr0 + row < NN)
            ((half8*)h1h)[(size_t)(gr0 + row) * 16 + (i & 15)] = ((const half8*)hs)[i];
    }

    const int arow = t >> 2, hd = t & 3;
    const int grow = gr0 + arow;
    float ps = 0.f, pd = 0.f;
    const half8*  hp8 = (const half8*)(hs + arow * 128 + hd * 32);
    const float4* s4  = (const float4*)(att_s + hd * 32);
    const float4* d4  = (const float4*)(att_d + hd * 32);
#pragma unroll
    for (int cc = 0; cc < 4; cc++) {
        const half8 hv = hp8[cc];
        const float4 a = s4[cc * 2], b = s4[cc * 2 + 1];
        const float4 c = d4[cc * 2], e = d4[cc * 2 + 1];
        ps += (float)hv[0]*a.x + (float)hv[1]*a.y + (float)hv[2]*a.z + (float)hv[3]*a.w
            + (float)hv[4]*b.x + (float)hv[5]*b.y + (float)hv[6]*b.z + (float)hv[7]*b.w;
        pd += (float)hv[0]*c.x + (float)hv[1]*c.y + (float)hv[2]*c.z + (float)hv[3]*c.w
            + (float)hv[4]*e.x + (float)hv[5]*e.y + (float)hv[6]*e.z + (float)hv[7]*e.w;
    }
    if (grow < NN) {
        as[grow * 4 + hd] = ps;
        ad[grow * 4 + hd] = pd;
    }
}

// ---------------------------------------------------------------------------
// MFMA GEMM2 + alpha2 (R13, verified 186.6)
// ---------------------------------------------------------------------------
__global__ __launch_bounds__(256) void gemm2_mfma_kernel(
    const _Float16* __restrict__ ah, const _Float16* __restrict__ w2t,
    const float* __restrict__ att_s, const float* __restrict__ att_d,
    _Float16* __restrict__ h2h, float* __restrict__ as, float* __restrict__ ad)
{
    __shared__ _Float16 lw[64 * 128];   // 16 KB swizzled W2^T
    __shared__ _Float16 hs[64 * 64];    // 8 KB
    const int t    = threadIdx.x;
    const int lane = t & 63;
    const int m    = lane & 15;
    const int q    = lane >> 4;
    const int wv   = t >> 6;
    const int gr0  = blockIdx.x * 64;
    const int rbase = gr0 + wv * 16;

    const int rme = rbase + m;
    const int rc  = rme < NN ? rme : NN - 1;
    const _Float16* ap = ah + (size_t)rc * 128 + q * 8;

    half8 av[4];
#pragma unroll
    for (int ks = 0; ks < 4; ks++) av[ks] = *(const half8*)(ap + ks * 32);

    {
        const int kb = t & 15;
        const int n0 = t >> 4;
#pragma unroll
        for (int it = 0; it < 4; it++) {
            const int n = n0 + it * 16;
            const uint4 v = *(const uint4*)(w2t + n * 128 + kb * 8);
            *(uint4*)((char*)lw + n * 256 + ((kb * 16) ^ ((n & 7) << 4))) = v;
        }
    }
    __syncthreads();

    floatx4 acc[4];
#pragma unroll
    for (int nt = 0; nt < 4; nt++) acc[nt] = (floatx4){0.f, 0.f, 0.f, 0.f};

    const int swz = (m & 7) << 4;
#pragma unroll
    for (int ks = 0; ks < 4; ks++) {
#pragma unroll
        for (int nt = 0; nt < 4; nt++) {
            const int n = nt * 16 + m;
            const half8 b = *(const half8*)((const char*)lw + n * 256 +
                                            ((ks * 64 + q * 16) ^ swz));
            acc[nt] = __builtin_amdgcn_mfma_f32_16x16x32_f16(av[ks], b, acc[nt], 0, 0, 0);
        }
    }

    const int lrow0 = wv * 16 + q * 4;
#pragma unroll
    for (int nt = 0; nt < 4; nt++)
#pragma unroll
        for (int r = 0; r < 4; r++)
            hs[(lrow0 + r) * 64 + nt * 16 + m] = (_Float16)acc[nt][r];
    __syncthreads();

#pragma unroll
    for (int i = t; i < 512; i += 256) {
        const int row = i >> 3;
        if (gr0 + row < NN)
            ((half8*)h2h)[(size_t)(gr0 + row) * 8 + (i & 7)] = ((const half8*)hs)[i];
    }

    const int arow = t >> 2, sg = t & 3;
    const int grow = gr0 + arow;
    float ps = 0.f, pd = 0.f;
    const half8*  hp8 = (const half8*)(hs + arow * 64 + sg * 16);
    const float4* s4  = (const float4*)(att_s + sg * 16);
    const float4* d4  = (const float4*)(att_d + sg * 16);
#pragma unroll
    for (int cc = 0; cc < 2; cc++) {
        const half8 hv = hp8[cc];
        const float4 a = s4[cc * 2], b = s4[cc * 2 + 1];
        const float4 c = d4[cc * 2], e = d4[cc * 2 + 1];
        ps += (float)hv[0]*a.x + (float)hv[1]*a.y + (float)hv[2]*a.z + (float)hv[3]*a.w
            + (float)hv[4]*b.x + (float)hv[5]*b.y + (float)hv[6]*b.z + (float)hv[7]*b.w;
        pd += (float)hv[0]*c.x + (float)hv[1]*c.y + (float)hv[2]*c.z + (float)hv[3]*c.w
            + (float)hv[4]*e.x + (float)hv[5]*e.y + (float)hv[6]*e.z + (float)hv[7]*e.w;
    }
    ps += __shfl_down(ps, 2);  pd += __shfl_down(pd, 2);
    ps += __shfl_down(ps, 1);  pd += __shfl_down(pd, 1);
    if (sg == 0 && grow < NN) { as[grow] = ps; ad[grow] = pd; }
}

// ---------------------------------------------------------------------------
// bin (R13, verified): grid-stride, padded bcnt, folded weight prep
// ---------------------------------------------------------------------------
__global__ __launch_bounds__(1024) void bin_kernel(const int* __restrict__ ei,
                                                   const float* __restrict__ W1,
                                                   const float* __restrict__ W2,
                                                   _Float16* __restrict__ w1t,
                                                   _Float16* __restrict__ w2t,
                                                   int* __restrict__ bcnt,
                                                   unsigned* __restrict__ pairs)
{
    if (blockIdx.x < 24) {
        const int idx = blockIdx.x * 1024 + threadIdx.x;
        if (idx < 16384) {
            const int k = idx >> 7, n = idx & 127;
            w1t[n * 128 + k] = (_Float16)W1[idx];
        } else {
            const int j = idx - 16384;
            const int k = j >> 6, n = j & 63;
            w2t[n * 128 + k] = (_Float16)W2[j];
        }
    }

    __shared__ int hist[NBUCK], base[NBUCK], cur[NBUCK];
    const int t = threadIdx.x;
    if (t < NBUCK) { hist[t] = 0; cur[t] = 0; }
    __syncthreads();

    for (int e = blockIdx.x * 1024 + t; e < NET; e += BINB * 1024) {
        const int d = (e < NE) ? ei[NE + e] : (e - NE);
        atomicAdd(&hist[d >> 8], 1);
    }
    __syncthreads();
    if (t < NBUCK && hist[t]) base[t] = atomicAdd(&bcnt[t * 16], hist[t]);
    __syncthreads();
    for (int e = blockIdx.x * 1024 + t; e < NET; e += BINB * 1024) {
        int s, d;
        if (e < NE) { s = ei[e]; d = ei[NE + e]; } else { s = d = e - NE; }
        const int bk = d >> 8;
        const int r = atomicAdd(&cur[bk], 1);
        pairs[(size_t)bk * MAXB + base[bk] + r] =
            (unsigned)s | ((unsigned)(d & 255) << 16);
    }
}

// ---------------------------------------------------------------------------
// bsort (R13, verified; 1024 threads — R10 showed 256t variant regresses)
// ---------------------------------------------------------------------------
__global__ __launch_bounds__(1024) void bsort_kernel(
    const int* __restrict__ bcnt, const unsigned* __restrict__ pairs,
    int* __restrict__ row_beg, int* __restrict__ row_end,
    int* __restrict__ col)
{
    __shared__ int hist[256], cur[256], sh[256];
    __shared__ int outl[MAXB];
    const int b = blockIdx.x, t = threadIdx.x;
    const int m = bcnt[b * 16];
    const int gbase = b * MAXB;
    if (t < 256) hist[t] = 0;
    __syncthreads();
    for (int i = t; i < m; i += 1024)
        atomicAdd(&hist[pairs[gbase + i] >> 16], 1);
    __syncthreads();
    if (t < 256) sh[t] = hist[t];
    __syncthreads();
#pragma unroll
    for (int off = 1; off < 256; off <<= 1) {
        int u = (t < 256 && t >= off) ? sh[t - off] : 0;
        __syncthreads();
        if (t < 256) sh[t] += u;
        __syncthreads();
    }
    if (t < 256) {
        const int ex = sh[t] - hist[t];
        cur[t] = ex;
        const int node = (b << 8) + t;
        if (node < NN) {
            row_beg[node] = gbase + ex;
            row_end[node] = gbase + ex + hist[t];
        }
    }
    __syncthreads();
    for (int i = t; i < m; i += 1024) {
        const unsigned p = pairs[gbase + i];
        const int r = atomicAdd(&cur[p >> 16], 1);
        outl[r] = (int)(p & 0xFFFFu);
    }
    __syncthreads();
    for (int i = t; i < m; i += 1024) col[gbase + i] = outl[i];
}

// ---------------------------------------------------------------------------
// Fused layer-1 tail (R10/R4 structure, verified 186.6)
// ---------------------------------------------------------------------------
__global__ __launch_bounds__(256) void agg1_fused_kernel(
    const int* __restrict__ row_beg, const int* __restrict__ row_end,
    const int* __restrict__ col, const unsigned* __restrict__ hh,
    const float* __restrict__ as1, const float* __restrict__ ad1,
    const float* __restrict__ b1, unsigned* __restrict__ acth)
{
    __shared__ float wbuf[4][64 * 4];   // [wave][edge*4+head], 4 KB
    const int wv   = threadIdx.x >> 6;
    const int d    = __builtin_amdgcn_readfirstlane((blockIdx.x * 256 + threadIdx.x) >> 6);
    const int lane = threadIdx.x & 63;
    const int head = lane >> 4;
    const int beg = row_beg[d], end = row_end[d];
    const float4 ad4 = ((const float4*)ad1)[d];
    float* wb = wbuf[wv];

    float acc0 = 0.f, acc1 = 0.f, den = 0.f;

    for (int jb = beg; jb < end; jb += 64) {
        const int cnt = min(64, end - jb);
        {
            const int sl = col[jb + min(lane, cnt - 1)];
            const float4 a = ((const float4*)as1)[sl];
            float4 w4;
            w4.x = __expf(lrelu(a.x + ad4.x));
            w4.y = __expf(lrelu(a.y + ad4.y));
            w4.z = __expf(lrelu(a.z + ad4.z));
            w4.w = __expf(lrelu(a.w + ad4.w));
            ((float4*)wb)[lane] = w4;
        }
        __asm__ volatile("s_waitcnt lgkmcnt(0)" ::: "memory");

        int k = 0;
        for (; k + 16 <= cnt; k += 16) {
            float    w[16];
            unsigned g[16];
#pragma unroll
            for (int u = 0; u < 16; u++) {
                const int s = col[jb + k + u];        // s_load (uniform)
                w[u] = wb[(k + u) * 4 + head];        // ds_read broadcast
                g[u] = hh[s * 64 + lane];             // saddr + voffset
            }
#pragma unroll
            for (int u = 0; u < 16; u++) {
                const float2 g2 = unpk16(g[u]);
                den  += w[u];
                acc0 += w[u] * g2.x;
                acc1 += w[u] * g2.y;
            }
        }
        for (; k + 4 <= cnt; k += 4) {
            float    w[4];
            unsigned g[4];
#pragma unroll
            for (int u = 0; u < 4; u++) {
                const int s = col[jb + k + u];
                w[u] = wb[(k + u) * 4 + head];
                g[u] = hh[s * 64 + lane];
            }
#pragma unroll
            for (int u = 0; u < 4; u++) {
                const float2 g2 = unpk16(g[u]);
                den  += w[u];
                acc0 += w[u] * g2.x;
                acc1 += w[u] * g2.y;
            }
        }
        for (; k < cnt; k++) {
            const float w = wb[k * 4 + head];
            const float2 g2 = unpk16(hh[col[jb + k] * 64 + lane]);
            den  += w;
            acc0 += w * g2.x;
            acc1 += w * g2.y;
        }
        __asm__ volatile("" ::: "memory");
    }
    const float2 bb  = ((const float2*)b1)[lane];
    const float  inv = 1.f / (den + 1e-16f);
    float v0 = acc0 * inv + bb.x;
    float v1 = acc1 * inv + bb.y;
    v0 = v0 > 0.f ? v0 : (__expf(v0) - 1.f);
    v1 = v1 > 0.f ? v1 : (__expf(v1) - 1.f);
    acth[d * 64 + lane] = pk16(v0, v1);
}

// ---------------------------------------------------------------------------
// Fused layer-2 tail — R19: R4 granularity (wave/node, 256t blocks) with
// 2 edges/wave full-width u32 gather; col reads stay SCALAR (s_load pair +
// cndmask select on half) — fixes R10's vector-col regression.
// ---------------------------------------------------------------------------
__global__ __launch_bounds__(256) void agg2_fused_kernel(
    const int* __restrict__ row_beg, const int* __restrict__ row_end,
    const int* __restrict__ col, const _Float16* __restrict__ h,
    const float* __restrict__ as2, const float* __restrict__ ad2,
    const float* __restrict__ b2, float* __restrict__ out)
{
    __shared__ float wbuf[4][64];   // 1 KB
    const int wv   = threadIdx.x >> 6;
    const int d    = __builtin_amdgcn_readfirstlane((blockIdx.x * 256 + threadIdx.x) >> 6);
    const int lane = threadIdx.x & 63;
    const int half = lane >> 5;      // edge slot 0/1
    const int c    = lane & 31;      // channel pair 2c,2c+1
    const int beg = row_beg[d], end = row_end[d];
    const float add = ad2[d];
    float* wb = wbuf[wv];
    const unsigned* __restrict__ h2 = (const unsigned*)h;

    float acc0 = 0.f, acc1 = 0.f, den = 0.f;

    for (int jb = beg; jb < end; jb += 64) {
        const int cnt = min(64, end - jb);
        {
            const int sl = col[jb + min(lane, cnt - 1)];
            wb[lane] = __expf(lrelu(as2[sl] + add));
        }
        __asm__ volatile("s_waitcnt lgkmcnt(0)" ::: "memory");

        int k = 0;
        for (; k + 16 <= cnt; k += 16) {
            float    w[8];
            unsigned g[8];
#pragma unroll
            for (int u = 0; u < 8; u++) {
                const int sA = col[jb + k + 2 * u];      // s_load (uniform)
                const int sB = col[jb + k + 2 * u + 1];  // s_load (uniform)
                const int s  = half ? sB : sA;           // cndmask
                w[u] = wb[k + 2 * u + half];             // ds_read
                g[u] = h2[(size_t)s * 32 + c];           // u32 = 2 channels
            }
#pragma unroll
            for (int u = 0; u < 8; u++) {
                const float2 g2 = unpk16(g[u]);
                den  += w[u];
                acc0 += w[u] * g2.x;
                acc1 += w[u] * g2.y;
            }
        }
        for (; k < cnt; k += 2) {
            const int sA = col[jb + k];
            const int sB = col[jb + min(k + 1, cnt - 1)];
            const int s  = half ? sB : sA;
            const float w = (k + half < cnt) ? wb[k + half] : 0.f;
            const float2 g2 = unpk16(h2[(size_t)s * 32 + c]);
            den  += w;
            acc0 += w * g2.x;
            acc1 += w * g2.y;
        }
        __asm__ volatile("" ::: "memory");
    }
    // combine the 2 edge slots (lanes c and c+32 hold the same channels)
    acc0 += __shfl_xor(acc0, 32);
    acc1 += __shfl_xor(acc1, 32);
    den  += __shfl_xor(den, 32);

    if (half == 0) {
        const float inv = 1.f / (den + 1e-16f);
        const float2 bb = ((const float2*)b2)[c];
        float2 o;
        o.x = acc0 * inv + bb.x;
        o.y = acc1 * inv + bb.y;
        ((float2*)out)[(size_t)d * 32 + c] = o;
    }
}

// ---------------------------------------------------------------------------
extern "C" void kernel_launch(void* const* d_in, const int* in_sizes, int n_in,
                              void* d_out, int out_size, void* d_ws, size_t ws_size,
                              hipStream_t stream)
{
    const float* x    = (const float*)d_in[0];
    const int*   ei   = (const int*)  d_in[1];
    const float* W1   = (const float*)d_in[2];
    const float* at_s1= (const float*)d_in[3];
    const float* at_d1= (const float*)d_in[4];
    const float* b1   = (const float*)d_in[5];
    const float* W2   = (const float*)d_in[6];
    const float* at_s2= (const float*)d_in[7];
    const float* at_d2= (const float*)d_in[8];
    const float* b2   = (const float*)d_in[9];
    float*       out  = (float*)d_out;

    const size_t NPAD = (size_t)NBUCK * MAXB;

    // workspace layout (~48 MB)
    float* fw   = (float*)d_ws;
    float* as1  = fw;                  // NN*4
    float* ad1  = as1  + NN * 4;       // NN*4
    float* as2  = ad1  + NN * 4;       // NN
    float* ad2  = as2  + NN;           // NN
    _Float16* h1h   = (_Float16*)(ad2 + NN);   // NN*128
    _Float16* act1h = h1h  + (size_t)NN * 128; // NN*128
    _Float16* h2h   = act1h+ (size_t)NN * 128; // NN*64
    _Float16* w1t   = h2h  + (size_t)NN * 64;  // 16384
    _Float16* w2t   = w1t  + 16384;            // 8192
    int*   row_beg = (int*)(w2t + 8192);       // NN
    int*   row_end = row_beg + NN;             // NN
    int*   col     = row_end + NN;             // NPAD
    int*   bcnt    = col + NPAD;               // 4096 ints (stride-16 padded)
    unsigned* pairs = (unsigned*)(bcnt + 4096); // NPAD

    hipMemsetAsync(bcnt, 0, 4096 * sizeof(int), stream);

    const int gemm_grid = (NN + 63) / 64;   // 782
    const int node_wave_grid = NN / 4;      // 12500 blocks (wave per node)

    bin_kernel  <<<BINB, 1024, 0, stream>>>(ei, W1, W2, w1t, w2t, bcnt, pairs);
    bsort_kernel<<<NBUCK, 1024, 0, stream>>>(bcnt, pairs, row_beg, row_end, col);

    // layer 1
    gemm1_mfma_kernel<<<gemm_grid, 256, 0, stream>>>(x, w1t, at_s1, at_d1, h1h, as1, ad1);
    agg1_fused_kernel<<<node_wave_grid, 256, 0, stream>>>(row_beg, row_end, col,
                        (const unsigned*)h1h, as1, ad1, b1, (unsigned*)act1h);

    // layer 2
    gemm2_mfma_kernel<<<gemm_grid, 256, 0, stream>>>(act1h, w2t, at_s2, at_d2, h2h, as2, ad2);
    agg2_fused_kernel<<<node_wave_grid, 256, 0, stream>>>(row_beg, row_end, col,
                        h2h, as2, ad2, b2, out);
}

// Round 12
// 185.598 us; speedup vs baseline: 5.4649x; 1.0199x over previous
//
#include <hip/hip_runtime.h>

#define NN    50000      // nodes
#define NE    800000     // edges (without self loops)
#define NET   850000     // NE + NN (with self loops)
#define NBUCK ((NN + 255) / 256)   // 196 dst-buckets of 256 nodes
#define MAXB  8192       // padded slots per bucket (avg 4352, sigma 66)
#define BINB  256        // bin grid blocks (grid-stride)

typedef __fp16 half2_t __attribute__((ext_vector_type(2)));
typedef _Float16 half8 __attribute__((ext_vector_type(8)));
typedef float floatx4 __attribute__((ext_vector_type(4)));

__device__ __forceinline__ float lrelu(float v) { return fmaxf(v, 0.2f * v); }
__device__ __forceinline__ unsigned pk16(float a, float b) {
    half2_t h = __builtin_amdgcn_cvt_pkrtz(a, b);
    return __builtin_bit_cast(unsigned, h);
}
__device__ __forceinline__ float2 unpk16(unsigned u) {
    half2_t h = __builtin_bit_cast(half2_t, u);
    return make_float2((float)h.x, (float)h.y);
}

// ---------------------------------------------------------------------------
// MFMA GEMM1 + alpha1 (R13, verified 186.6): W1^T staged in LDS, x hoisted.
// ---------------------------------------------------------------------------
__global__ __launch_bounds__(256) void gemm1_mfma_kernel(
    const float* __restrict__ x, const _Float16* __restrict__ w1t,
    const float* __restrict__ att_s, const float* __restrict__ att_d,
    _Float16* __restrict__ h1h, float* __restrict__ as, float* __restrict__ ad)
{
    __shared__ _Float16 lw[128 * 128];  // 32 KB swizzled W1^T
    __shared__ _Float16 hs[64 * 128];   // 16 KB
    const int t    = threadIdx.x;
    const int lane = t & 63;
    const int m    = lane & 15;
    const int q    = lane >> 4;
    const int wv   = t >> 6;
    const int gr0  = blockIdx.x * 64;
    const int rbase = gr0 + wv * 16;

    const int rme = rbase + m;
    const int rc  = rme < NN ? rme : NN - 1;
    const float* ap = x + (size_t)rc * 128 + q * 8;

    float4 f0[4], f1[4];
#pragma unroll
    for (int ks = 0; ks < 4; ks++) {
        f0[ks] = *(const float4*)(ap + ks * 32);
        f1[ks] = *(const float4*)(ap + ks * 32 + 4);
    }

    {
        const int kb = t & 15;
        const int n0 = t >> 4;
#pragma unroll
        for (int it = 0; it < 8; it++) {
            const int n = n0 + it * 16;
            const uint4 v = *(const uint4*)(w1t + n * 128 + kb * 8);
            *(uint4*)((char*)lw + n * 256 + ((kb * 16) ^ ((n & 7) << 4))) = v;
        }
    }
    __syncthreads();

    floatx4 acc[8];
#pragma unroll
    for (int nt = 0; nt < 8; nt++) acc[nt] = (floatx4){0.f, 0.f, 0.f, 0.f};

    const int swz = (m & 7) << 4;
#pragma unroll
    for (int ks = 0; ks < 4; ks++) {
        const uint4 au = make_uint4(pk16(f0[ks].x, f0[ks].y), pk16(f0[ks].z, f0[ks].w),
                                    pk16(f1[ks].x, f1[ks].y), pk16(f1[ks].z, f1[ks].w));
        const half8 a = __builtin_bit_cast(half8, au);
#pragma unroll
        for (int nt = 0; nt < 8; nt++) {
            const int n = nt * 16 + m;
            const half8 b = *(const half8*)((const char*)lw + n * 256 +
                                            ((ks * 64 + q * 16) ^ swz));
            acc[nt] = __builtin_amdgcn_mfma_f32_16x16x32_f16(a, b, acc[nt], 0, 0, 0);
        }
    }

    const int lrow0 = wv * 16 + q * 4;
#pragma unroll
    for (int nt = 0; nt < 8; nt++)
#pragma unroll
        for (int r = 0; r < 4; r++)
            hs[(lrow0 + r) * 128 + nt * 16 + m] = (_Float16)acc[nt][r];
    __syncthreads();

#pragma unroll
    for (int i = t; i < 1024; i += 256) {
        const int row = i >> 4;
        if (gr0 + row < NN)
            ((half8*)h1h)[(size_t)(gr0 + row) * 16 + (i & 15)] = ((const half8*)hs)[i];
    }

    const int arow = t >> 2, hd = t & 3;
    const int grow = gr0 + arow;
    float ps = 0.f, pd = 0.f;
    const half8*  hp8 = (const half8*)(hs + arow * 128 + hd * 32);
    const float4* s4  = (const float4*)(att_s + hd * 32);
    const float4* d4  = (const float4*)(att_d + hd * 32);
#pragma unroll
    for (int cc = 0; cc < 4; cc++) {
        const half8 hv = hp8[cc];
        const float4 a = s4[cc * 2], b = s4[cc * 2 + 1];
        const float4 c = d4[cc * 2], e = d4[cc * 2 + 1];
        ps += (float)hv[0]*a.x + (float)hv[1]*a.y + (float)hv[2]*a.z + (float)hv[3]*a.w
            + (float)hv[4]*b.x + (float)hv[5]*b.y + (float)hv[6]*b.z + (float)hv[7]*b.w;
        pd += (float)hv[0]*c.x + (float)hv[1]*c.y + (float)hv[2]*c.z + (float)hv[3]*c.w
            + (float)hv[4]*e.x + (float)hv[5]*e.y + (float)hv[6]*e.z + (float)hv[7]*e.w;
    }
    if (grow < NN) {
        as[grow * 4 + hd] = ps;
        ad[grow * 4 + hd] = pd;
    }
}

// ---------------------------------------------------------------------------
// MFMA GEMM2 + alpha2 (R13, verified 186.6)
// ---------------------------------------------------------------------------
__global__ __launch_bounds__(256) void gemm2_mfma_kernel(
    const _Float16* __restrict__ ah, const _Float16* __restrict__ w2t,
    const float* __restrict__ att_s, const float* __restrict__ att_d,
    _Float16* __restrict__ h2h, float* __restrict__ as, float* __restrict__ ad)
{
    __shared__ _Float16 lw[64 * 128];   // 16 KB swizzled W2^T
    __shared__ _Float16 hs[64 * 64];    // 8 KB
    const int t    = threadIdx.x;
    const int lane = t & 63;
    const int m    = lane & 15;
    const int q    = lane >> 4;
    const int wv   = t >> 6;
    const int gr0  = blockIdx.x * 64;
    const int rbase = gr0 + wv * 16;

    const int rme = rbase + m;
    const int rc  = rme < NN ? rme : NN - 1;
    const _Float16* ap = ah + (size_t)rc * 128 + q * 8;

    half8 av[4];
#pragma unroll
    for (int ks = 0; ks < 4; ks++) av[ks] = *(const half8*)(ap + ks * 32);

    {
        const int kb = t & 15;
        const int n0 = t >> 4;
#pragma unroll
        for (int it = 0; it < 4; it++) {
            const int n = n0 + it * 16;
            const uint4 v = *(const uint4*)(w2t + n * 128 + kb * 8);
            *(uint4*)((char*)lw + n * 256 + ((kb * 16) ^ ((n & 7) << 4))) = v;
        }
    }
    __syncthreads();

    floatx4 acc[4];
#pragma unroll
    for (int nt = 0; nt < 4; nt++) acc[nt] = (floatx4){0.f, 0.f, 0.f, 0.f};

    const int swz = (m & 7) << 4;
#pragma unroll
    for (int ks = 0; ks < 4; ks++) {
#pragma unroll
        for (int nt = 0; nt < 4; nt++) {
            const int n = nt * 16 + m;
            const half8 b = *(const half8*)((const char*)lw + n * 256 +
                                            ((ks * 64 + q * 16) ^ swz));
            acc[nt] = __builtin_amdgcn_mfma_f32_16x16x32_f16(av[ks], b, acc[nt], 0, 0, 0);
        }
    }

    const int lrow0 = wv * 16 + q * 4;
#pragma unroll
    for (int nt = 0; nt < 4; nt++)
#pragma unroll
        for (int r = 0; r < 4; r++)
            hs[(lrow0 + r) * 64 + nt * 16 + m] = (_Float16)acc[nt][r];
    __syncthreads();

#pragma unroll
    for (int i = t; i < 512; i += 256) {
        const int row = i >> 3;
        if (gr0 + row < NN)
            ((half8*)h2h)[(size_t)(gr0 + row) * 8 + (i & 7)] = ((const half8*)hs)[i];
    }

    const int arow = t >> 2, sg = t & 3;
    const int grow = gr0 + arow;
    float ps = 0.f, pd = 0.f;
    const half8*  hp8 = (const half8*)(hs + arow * 64 + sg * 16);
    const float4* s4  = (const float4*)(att_s + sg * 16);
    const float4* d4  = (const float4*)(att_d + sg * 16);
#pragma unroll
    for (int cc = 0; cc < 2; cc++) {
        const half8 hv = hp8[cc];
        const float4 a = s4[cc * 2], b = s4[cc * 2 + 1];
        const float4 c = d4[cc * 2], e = d4[cc * 2 + 1];
        ps += (float)hv[0]*a.x + (float)hv[1]*a.y + (float)hv[2]*a.z + (float)hv[3]*a.w
            + (float)hv[4]*b.x + (float)hv[5]*b.y + (float)hv[6]*b.z + (float)hv[7]*b.w;
        pd += (float)hv[0]*c.x + (float)hv[1]*c.y + (float)hv[2]*c.z + (float)hv[3]*c.w
            + (float)hv[4]*e.x + (float)hv[5]*e.y + (float)hv[6]*e.z + (float)hv[7]*e.w;
    }
    ps += __shfl_down(ps, 2);  pd += __shfl_down(pd, 2);
    ps += __shfl_down(ps, 1);  pd += __shfl_down(pd, 1);
    if (sg == 0 && grow < NN) { as[grow] = ps; ad[grow] = pd; }
}

// ---------------------------------------------------------------------------
// bin (R13, verified): grid-stride, padded bcnt, folded weight prep
// ---------------------------------------------------------------------------
__global__ __launch_bounds__(1024) void bin_kernel(const int* __restrict__ ei,
                                                   const float* __restrict__ W1,
                                                   const float* __restrict__ W2,
                                                   _Float16* __restrict__ w1t,
                                                   _Float16* __restrict__ w2t,
                                                   int* __restrict__ bcnt,
                                                   unsigned* __restrict__ pairs)
{
    if (blockIdx.x < 24) {
        const int idx = blockIdx.x * 1024 + threadIdx.x;
        if (idx < 16384) {
            const int k = idx >> 7, n = idx & 127;
            w1t[n * 128 + k] = (_Float16)W1[idx];
        } else {
            const int j = idx - 16384;
            const int k = j >> 6, n = j & 63;
            w2t[n * 128 + k] = (_Float16)W2[j];
        }
    }

    __shared__ int hist[NBUCK], base[NBUCK], cur[NBUCK];
    const int t = threadIdx.x;
    if (t < NBUCK) { hist[t] = 0; cur[t] = 0; }
    __syncthreads();

    for (int e = blockIdx.x * 1024 + t; e < NET; e += BINB * 1024) {
        const int d = (e < NE) ? ei[NE + e] : (e - NE);
        atomicAdd(&hist[d >> 8], 1);
    }
    __syncthreads();
    if (t < NBUCK && hist[t]) base[t] = atomicAdd(&bcnt[t * 16], hist[t]);
    __syncthreads();
    for (int e = blockIdx.x * 1024 + t; e < NET; e += BINB * 1024) {
        int s, d;
        if (e < NE) { s = ei[e]; d = ei[NE + e]; } else { s = d = e - NE; }
        const int bk = d >> 8;
        const int r = atomicAdd(&cur[bk], 1);
        pairs[(size_t)bk * MAXB + base[bk] + r] =
            (unsigned)s | ((unsigned)(d & 255) << 16);
    }
}

// ---------------------------------------------------------------------------
// bsort (R13, verified; 1024 threads)
// ---------------------------------------------------------------------------
__global__ __launch_bounds__(1024) void bsort_kernel(
    const int* __restrict__ bcnt, const unsigned* __restrict__ pairs,
    int* __restrict__ row_beg, int* __restrict__ row_end,
    int* __restrict__ col)
{
    __shared__ int hist[256], cur[256], sh[256];
    __shared__ int outl[MAXB];
    const int b = blockIdx.x, t = threadIdx.x;
    const int m = bcnt[b * 16];
    const int gbase = b * MAXB;
    if (t < 256) hist[t] = 0;
    __syncthreads();
    for (int i = t; i < m; i += 1024)
        atomicAdd(&hist[pairs[gbase + i] >> 16], 1);
    __syncthreads();
    if (t < 256) sh[t] = hist[t];
    __syncthreads();
#pragma unroll
    for (int off = 1; off < 256; off <<= 1) {
        int u = (t < 256 && t >= off) ? sh[t - off] : 0;
        __syncthreads();
        if (t < 256) sh[t] += u;
        __syncthreads();
    }
    if (t < 256) {
        const int ex = sh[t] - hist[t];
        cur[t] = ex;
        const int node = (b << 8) + t;
        if (node < NN) {
            row_beg[node] = gbase + ex;
            row_end[node] = gbase + ex + hist[t];
        }
    }
    __syncthreads();
    for (int i = t; i < m; i += 1024) {
        const unsigned p = pairs[gbase + i];
        const int r = atomicAdd(&cur[p >> 16], 1);
        outl[r] = (int)(p & 0xFFFFu);
    }
    __syncthreads();
    for (int i = t; i < m; i += 1024) col[gbase + i] = outl[i];
}

// ---------------------------------------------------------------------------
// Fused layer-1 tail (R10/R4 structure, verified 186.6)
// ---------------------------------------------------------------------------
__global__ __launch_bounds__(256) void agg1_fused_kernel(
    const int* __restrict__ row_beg, const int* __restrict__ row_end,
    const int* __restrict__ col, const unsigned* __restrict__ hh,
    const float* __restrict__ as1, const float* __restrict__ ad1,
    const float* __restrict__ b1, unsigned* __restrict__ acth)
{
    __shared__ float wbuf[4][64 * 4];   // [wave][edge*4+head], 4 KB
    const int wv   = threadIdx.x >> 6;
    const int d    = __builtin_amdgcn_readfirstlane((blockIdx.x * 256 + threadIdx.x) >> 6);
    const int lane = threadIdx.x & 63;
    const int head = lane >> 4;
    const int beg = row_beg[d], end = row_end[d];
    const float4 ad4 = ((const float4*)ad1)[d];
    float* wb = wbuf[wv];

    float acc0 = 0.f, acc1 = 0.f, den = 0.f;

    for (int jb = beg; jb < end; jb += 64) {
        const int cnt = min(64, end - jb);
        {
            const int sl = col[jb + min(lane, cnt - 1)];
            const float4 a = ((const float4*)as1)[sl];
            float4 w4;
            w4.x = __expf(lrelu(a.x + ad4.x));
            w4.y = __expf(lrelu(a.y + ad4.y));
            w4.z = __expf(lrelu(a.z + ad4.z));
            w4.w = __expf(lrelu(a.w + ad4.w));
            ((float4*)wb)[lane] = w4;
        }
        __asm__ volatile("s_waitcnt lgkmcnt(0)" ::: "memory");

        int k = 0;
        for (; k + 16 <= cnt; k += 16) {
            float    w[16];
            unsigned g[16];
#pragma unroll
            for (int u = 0; u < 16; u++) {
                const int s = col[jb + k + u];        // s_load (uniform)
                w[u] = wb[(k + u) * 4 + head];        // ds_read broadcast
                g[u] = hh[s * 64 + lane];             // saddr + voffset
            }
#pragma unroll
            for (int u = 0; u < 16; u++) {
                const float2 g2 = unpk16(g[u]);
                den  += w[u];
                acc0 += w[u] * g2.x;
                acc1 += w[u] * g2.y;
            }
        }
        for (; k + 4 <= cnt; k += 4) {
            float    w[4];
            unsigned g[4];
#pragma unroll
            for (int u = 0; u < 4; u++) {
                const int s = col[jb + k + u];
                w[u] = wb[(k + u) * 4 + head];
                g[u] = hh[s * 64 + lane];
            }
#pragma unroll
            for (int u = 0; u < 4; u++) {
                const float2 g2 = unpk16(g[u]);
                den  += w[u];
                acc0 += w[u] * g2.x;
                acc1 += w[u] * g2.y;
            }
        }
        for (; k < cnt; k++) {
            const float w = wb[k * 4 + head];
            const float2 g2 = unpk16(hh[col[jb + k] * 64 + lane]);
            den  += w;
            acc0 += w * g2.x;
            acc1 += w * g2.y;
        }
        __asm__ volatile("" ::: "memory");
    }
    const float2 bb  = ((const float2*)b1)[lane];
    const float  inv = 1.f / (den + 1e-16f);
    float v0 = acc0 * inv + bb.x;
    float v1 = acc1 * inv + bb.y;
    v0 = v0 > 0.f ? v0 : (__expf(v0) - 1.f);
    v1 = v1 > 0.f ? v1 : (__expf(v1) - 1.f);
    acth[d * 64 + lane] = pk16(v0, v1);
}

// ---------------------------------------------------------------------------
// Fused layer-2 tail (R10/R4 structure, verified 186.6)
// ---------------------------------------------------------------------------
__global__ __launch_bounds__(256) void agg2_fused_kernel(
    const int* __restrict__ row_beg, const int* __restrict__ row_end,
    const int* __restrict__ col, const _Float16* __restrict__ h,
    const float* __restrict__ as2, const float* __restrict__ ad2,
    const float* __restrict__ b2, float* __restrict__ out)
{
    __shared__ float wbuf[4][64];   // 1 KB
    const int wv   = threadIdx.x >> 6;
    const int d    = __builtin_amdgcn_readfirstlane((blockIdx.x * 256 + threadIdx.x) >> 6);
    const int lane = threadIdx.x & 63;
    const int beg = row_beg[d], end = row_end[d];
    const float add = ad2[d];
    float* wb = wbuf[wv];

    float acc = 0.f, den = 0.f;

    for (int jb = beg; jb < end; jb += 64) {
        const int cnt = min(64, end - jb);
        {
            const int sl = col[jb + min(lane, cnt - 1)];
            wb[lane] = __expf(lrelu(as2[sl] + add));
        }
        __asm__ volatile("s_waitcnt lgkmcnt(0)" ::: "memory");

        int k = 0;
        for (; k + 16 <= cnt; k += 16) {
            float w[16], g[16];
#pragma unroll
            for (int u = 0; u < 16; u++) {
                const int s = col[jb + k + u];
                w[u] = wb[k + u];
                g[u] = (float)h[s * 64 + lane];
            }
#pragma unroll
            for (int u = 0; u < 16; u++) {
                den += w[u];
                acc += w[u] * g[u];
            }
        }
        for (; k + 4 <= cnt; k += 4) {
            float w[4], g[4];
#pragma unroll
            for (int u = 0; u < 4; u++) {
                const int s = col[jb + k + u];
                w[u] = wb[k + u];
                g[u] = (float)h[s * 64 + lane];
            }
#pragma unroll
            for (int u = 0; u < 4; u++) {
                den += w[u];
                acc += w[u] * g[u];
            }
        }
        for (; k < cnt; k++) {
            const float w = wb[k];
            den += w;
            acc += w * (float)h[col[jb + k] * 64 + lane];
        }
        __asm__ volatile("" ::: "memory");
    }
    out[d * 64 + lane] = acc / (den + 1e-16f) + b2[lane];
}

// ---------------------------------------------------------------------------
extern "C" void kernel_launch(void* const* d_in, const int* in_sizes, int n_in,
                              void* d_out, int out_size, void* d_ws, size_t ws_size,
                              hipStream_t stream)
{
    const float* x    = (const float*)d_in[0];
    const int*   ei   = (const int*)  d_in[1];
    const float* W1   = (const float*)d_in[2];
    const float* at_s1= (const float*)d_in[3];
    const float* at_d1= (const float*)d_in[4];
    const float* b1   = (const float*)d_in[5];
    const float* W2   = (const float*)d_in[6];
    const float* at_s2= (const float*)d_in[7];
    const float* at_d2= (const float*)d_in[8];
    const float* b2   = (const float*)d_in[9];
    float*       out  = (float*)d_out;

    const size_t NPAD = (size_t)NBUCK * MAXB;

    // workspace layout (~48 MB)
    float* fw   = (float*)d_ws;
    float* as1  = fw;                  // NN*4
    float* ad1  = as1  + NN * 4;       // NN*4
    float* as2  = ad1  + NN * 4;       // NN
    float* ad2  = as2  + NN;           // NN
    _Float16* h1h   = (_Float16*)(ad2 + NN);   // NN*128
    _Float16* act1h = h1h  + (size_t)NN * 128; // NN*128
    _Float16* h2h   = act1h+ (size_t)NN * 128; // NN*64
    _Float16* w1t   = h2h  + (size_t)NN * 64;  // 16384
    _Float16* w2t   = w1t  + 16384;            // 8192
    int*   row_beg = (int*)(w2t + 8192);       // NN
    int*   row_end = row_beg + NN;             // NN
    int*   col     = row_end + NN;             // NPAD
    int*   bcnt    = col + NPAD;               // 4096 ints (stride-16 padded)
    unsigned* pairs = (unsigned*)(bcnt + 4096); // NPAD

    hipMemsetAsync(bcnt, 0, 4096 * sizeof(int), stream);

    const int gemm_grid = (NN + 63) / 64;   // 782
    const int node_wave_grid = NN / 4;      // 12500 blocks (wave per node)

    bin_kernel  <<<BINB, 1024, 0, stream>>>(ei, W1, W2, w1t, w2t, bcnt, pairs);
    bsort_kernel<<<NBUCK, 1024, 0, stream>>>(bcnt, pairs, row_beg, row_end, col);

    // layer 1
    gemm1_mfma_kernel<<<gemm_grid, 256, 0, stream>>>(x, w1t, at_s1, at_d1, h1h, as1, ad1);
    agg1_fused_kernel<<<node_wave_grid, 256, 0, stream>>>(row_beg, row_end, col,
                        (const unsigned*)h1h, as1, ad1, b1, (unsigned*)act1h);

    // layer 2
    gemm2_mfma_kernel<<<gemm_grid, 256, 0, stream>>>(act1h, w2t, at_s2, at_d2, h2h, as2, ad2);
    agg2_fused_kernel<<<node_wave_grid, 256, 0, stream>>>(row_beg, row_end, col,
                        h2h, as2, ad2, b2, out);
}